// Round 8
// baseline (24543.636 us; speedup 1.0000x reference)
//
#include <hip/hip_runtime.h>

#define BB 16
#define NN 2048
#define CC 64
#define KNN 20
#define OUTC 1024

// ====== xx: numpy pairwise_sum(n=64, 8-acc path) over RN(f^2) ======
__global__ __launch_bounds__(256) void xx32_kernel(const float* __restrict__ F,
                                                   float* __restrict__ xxf) {
  int p = blockIdx.x * 256 + threadIdx.x;
  const float* f = F + (size_t)p * CC;
  float t[64];
#pragma unroll
  for (int c = 0; c < 64; ++c) t[c] = f[c] * f[c];
  float r[8];
#pragma unroll
  for (int j = 0; j < 8; ++j) r[j] = t[j];
#pragma unroll
  for (int i = 8; i < 64; i += 8)
#pragma unroll
    for (int j = 0; j < 8; ++j) r[j] += t[i + j];
  float res = ((r[0] + r[1]) + (r[2] + r[3])) + ((r[4] + r[5]) + (r[6] + r[7]));
  xxf[p] = res;
}

// ====== kNN: BLAS-sgemm-emulated f32 inner (sequential ascending FMA chain),
//        f32 combine (2I - xn) - xm, top-k with tie -> lower index ======
__global__ __launch_bounds__(64) void knn32_kernel(const float* __restrict__ F,
                                                   const float* __restrict__ xxf,
                                                   int* __restrict__ idx) {
  __shared__ float qrow[64];
  __shared__ float xxs[NN];
  __shared__ float distf[NN];
  int b = blockIdx.y, n0 = blockIdx.x * 64, t = threadIdx.x;
  for (int v = t; v < NN; v += 64) xxs[v] = xxf[b * NN + v];
  __syncthreads();
  for (int r = 0; r < 64; ++r) {
    int n = n0 + r;
    qrow[t] = F[((size_t)(b * NN + n)) * CC + t];
    __syncthreads();
    float xfn = xxs[n];
    for (int j = 0; j < 32; ++j) {
      int m = t * 32 + j;
      const float* fr = F + ((size_t)(b * NN + m)) * CC;
      float a[64];
#pragma unroll
      for (int c4 = 0; c4 < 16; ++c4) *(float4*)&a[c4 * 4] = *(const float4*)(fr + c4 * 4);
      float I = 0.0f;
#pragma unroll
      for (int c = 0; c < 64; ++c) I = fmaf(qrow[c], a[c], I);  // seq ascending
      distf[m] = (2.0f * I - xfn) - xxs[m];
    }
    __syncthreads();
    for (int k = 0; k < KNN; ++k) {
      float bv = -1e37f;
      int bi = 1 << 30;
      for (int j = 0; j < 32; ++j) {
        int m = t + j * 64;
        float v = distf[m];
        if (v > bv || (v == bv && m < bi)) { bv = v; bi = m; }
      }
      for (int off = 32; off; off >>= 1) {
        float v2 = __shfl_down(bv, off);
        int i2 = __shfl_down(bi, off);
        if (v2 > bv || (v2 == bv && i2 < bi)) { bv = v2; bi = i2; }
      }
      if (t == 0) {
        idx[((size_t)(b * NN + n)) * KNN + k] = bi;
        distf[bi] = -3.0e38f;
      }
      __syncthreads();
    }
    __syncthreads();
  }
}

// ====== h chain: BLAS-emulated f32 sequential ascending FMA over e=0..127 ======
__device__ __forceinline__ float h_chain(const float* __restrict__ wo,
                                         const float* __restrict__ fnp,
                                         const float* __restrict__ fm) {
  float acc = 0.0f;
#pragma unroll
  for (int c = 0; c < 64; ++c) acc = fmaf(wo[c], fm[c] - fnp[c], acc);
#pragma unroll
  for (int c = 0; c < 64; ++c) acc = fmaf(wo[64 + c], fnp[c], acc);
  return acc;
}

// ====== EdgeConv stats: f64 sums of the f32 BLAS-chain h values ======
__global__ __launch_bounds__(256) void stats_np(const float* __restrict__ F,
                                                const float* __restrict__ W,
                                                const int* __restrict__ idx,
                                                double* __restrict__ sums) {
  __shared__ float Wl[64 * 129];
  __shared__ float Fn[64 * 65];
  __shared__ double rs[256], rss[256];
  int b = blockIdx.y, n0 = blockIdx.x * 64, t = threadIdx.x;
  for (int j = 0; j < 32; ++j) {
    int v = t + 256 * j;
    int o = v >> 7, e = v & 127;
    Wl[o * 129 + e] = W[o * 128 + e];
  }
  for (int j = 0; j < 4; ++j) {
    int v = t + 256 * j;
    int row = v >> 4, c4 = (v & 15) * 4;
    float4 val = *(const float4*)(F + ((size_t)(b * NN + n0 + row)) * CC + c4);
    Fn[row * 65 + c4] = val.x; Fn[row * 65 + c4 + 1] = val.y;
    Fn[row * 65 + c4 + 2] = val.z; Fn[row * 65 + c4 + 3] = val.w;
  }
  __syncthreads();
  int o = t & 63, g4 = t >> 6;
  const float* wo = &Wl[o * 129];
  double s = 0.0, ss = 0.0;
  for (int i = 0; i < 16; ++i) {
    int n = n0 + g4 * 16 + i;
    const float* fnp = &Fn[(g4 * 16 + i) * 65];
    const int* ip = idx + ((size_t)(b * NN + n)) * KNN;
    for (int k = 0; k < KNN; ++k) {
      const float* fmp = F + ((size_t)(b * NN + ip[k])) * CC;
      float fm[64];
#pragma unroll
      for (int c4 = 0; c4 < 16; ++c4) *(float4*)&fm[c4 * 4] = *(const float4*)(fmp + c4 * 4);
      float h = h_chain(wo, fnp, fm);
      s += (double)h;
      ss += (double)h * (double)h;
    }
  }
  rs[t] = s; rss[t] = ss;
  __syncthreads();
  if (t < 64) {
    double a = rs[t] + rs[t + 64] + rs[t + 128] + rs[t + 192];
    double q = rss[t] + rss[t + 64] + rss[t + 128] + rss[t + 192];
    atomicAdd(&sums[o], a);
    atomicAdd(&sums[64 + o], q);
  }
}

// ====== BN finalize for edge layers: f32 mean + f32 rs (np op sequence) ======
__global__ void finalize_np(const double* __restrict__ sums, double cntinv,
                            float* __restrict__ mrs) {
  int c = threadIdx.x;  // 64
  double mean = sums[c] * cntinv;
  double var = sums[64 + c] * cntinv - mean * mean;
  float m32 = (float)mean;
  float v32 = (float)var;
  mrs[c] = m32;
  mrs[64 + c] = 1.0f / sqrtf(v32 + 1e-5f);
}

// ====== EdgeConv apply: f32 BLAS-chain h + f32 normalize chain + max_k ======
__global__ __launch_bounds__(256) void apply_np(const float* __restrict__ F,
                                                const float* __restrict__ W,
                                                const int* __restrict__ idx,
                                                const float* __restrict__ mrs,
                                                const float* __restrict__ gv,
                                                const float* __restrict__ bv,
                                                float* __restrict__ Fo) {
  __shared__ float Wl[64 * 129];
  __shared__ float Fn[64 * 65];
  int b = blockIdx.y, n0 = blockIdx.x * 64, t = threadIdx.x;
  for (int j = 0; j < 32; ++j) {
    int v = t + 256 * j;
    int o = v >> 7, e = v & 127;
    Wl[o * 129 + e] = W[o * 128 + e];
  }
  for (int j = 0; j < 4; ++j) {
    int v = t + 256 * j;
    int row = v >> 4, c4 = (v & 15) * 4;
    float4 val = *(const float4*)(F + ((size_t)(b * NN + n0 + row)) * CC + c4);
    Fn[row * 65 + c4] = val.x; Fn[row * 65 + c4 + 1] = val.y;
    Fn[row * 65 + c4 + 2] = val.z; Fn[row * 65 + c4 + 3] = val.w;
  }
  __syncthreads();
  int o = t & 63, g4 = t >> 6;
  float m32 = mrs[o], rs32 = mrs[64 + o];
  float gg = gv[o], bb = bv[o];
  const float* wo = &Wl[o * 129];
  for (int i = 0; i < 16; ++i) {
    int n = n0 + g4 * 16 + i;
    const float* fnp = &Fn[(g4 * 16 + i) * 65];
    const int* ip = idx + ((size_t)(b * NN + n)) * KNN;
    float mx = -3.0e38f;
    for (int k = 0; k < KNN; ++k) {
      const float* fmp = F + ((size_t)(b * NN + ip[k])) * CC;
      float fm[64];
#pragma unroll
      for (int c4 = 0; c4 < 16; ++c4) *(float4*)&fm[c4 * 4] = *(const float4*)(fmp + c4 * 4);
      float h = h_chain(wo, fnp, fm);
      float d = h - m32;
      d = d * rs32;
      d = d * gg;
      float y = d + bb;
      y = y >= 0.f ? y : 0.2f * y;
      mx = fmaxf(mx, y);
    }
    Fo[((size_t)(b * NN + n)) * CC + o] = mx;
  }
}

// ====== final projection stats (f64 exact, value-robust) ======
__global__ __launch_bounds__(256) void fstats_bf(const float* __restrict__ F1,
                                                 const float* __restrict__ F2,
                                                 const float* __restrict__ F3,
                                                 const float* __restrict__ Wf,
                                                 double* __restrict__ sums) {
  __shared__ float Wl[64 * 193];
  __shared__ double rs[256], rss[256];
  int b = blockIdx.y, o0 = blockIdx.x * 64, t = threadIdx.x;
  for (int j = 0; j < 48; ++j) {
    int v = t + 256 * j;
    int oo = v / 192, c = v - oo * 192;
    Wl[oo * 193 + c] = Wf[(size_t)(o0 + oo) * 192 + c];
  }
  __syncthreads();
  int o = t & 63, g = t >> 6;
  double s = 0.0, ss = 0.0;
  for (int n = g; n < NN; n += 4) {
    size_t nb = ((size_t)(b * NN + n)) * CC;
    double h = 0.0;
#pragma unroll 8
    for (int c = 0; c < 64; ++c) h = fma((double)Wl[o * 193 + c], (double)F1[nb + c], h);
#pragma unroll 8
    for (int c = 0; c < 64; ++c) h = fma((double)Wl[o * 193 + 64 + c], (double)F2[nb + c], h);
#pragma unroll 8
    for (int c = 0; c < 64; ++c) h = fma((double)Wl[o * 193 + 128 + c], (double)F3[nb + c], h);
    s += h;
    ss += h * h;
  }
  rs[t] = s; rss[t] = ss;
  __syncthreads();
  if (t < 64) {
    double a = rs[t] + rs[t + 64] + rs[t + 128] + rs[t + 192];
    double q = rss[t] + rss[t + 64] + rss[t + 128] + rss[t + 192];
    atomicAdd(&sums[o0 + o], a);
    atomicAdd(&sums[1024 + o0 + o], q);
  }
}

// ====== BN finalize (f64, final layer) ======
__global__ void finalize_d(const double* __restrict__ sums,
                           const float* __restrict__ g,
                           const float* __restrict__ bb, double cntinv,
                           int nch, int stride, double* __restrict__ scsh) {
  int c = blockIdx.x * blockDim.x + threadIdx.x;
  if (c < nch) {
    double mean = sums[c] * cntinv;
    double var = sums[stride + c] * cntinv - mean * mean;
    double sc = (double)g[c] / sqrt(var + 1e-5);
    scsh[c] = sc;
    scsh[stride + c] = (double)bb[c] - mean * sc;
  }
}

// ====== final apply (f64 exact) ======
__global__ __launch_bounds__(256) void fapply_bf(const float* __restrict__ F1,
                                                 const float* __restrict__ F2,
                                                 const float* __restrict__ F3,
                                                 const float* __restrict__ Wf,
                                                 const double* __restrict__ scsh,
                                                 float* __restrict__ out) {
  __shared__ float Wl[64 * 193];
  __shared__ double redm[4][64];
  int b = blockIdx.y, o0 = blockIdx.x * 64, t = threadIdx.x;
  for (int j = 0; j < 48; ++j) {
    int v = t + 256 * j;
    int oo = v / 192, c = v - oo * 192;
    Wl[oo * 193 + c] = Wf[(size_t)(o0 + oo) * 192 + c];
  }
  __syncthreads();
  int o = t & 63, g = t >> 6;
  double sc = scsh[o0 + o], sh = scsh[1024 + o0 + o];
  double mx = -1e300;
  for (int n = g; n < NN; n += 4) {
    size_t nb = ((size_t)(b * NN + n)) * CC;
    double h = 0.0;
#pragma unroll 8
    for (int c = 0; c < 64; ++c) h = fma((double)Wl[o * 193 + c], (double)F1[nb + c], h);
#pragma unroll 8
    for (int c = 0; c < 64; ++c) h = fma((double)Wl[o * 193 + 64 + c], (double)F2[nb + c], h);
#pragma unroll 8
    for (int c = 0; c < 64; ++c) h = fma((double)Wl[o * 193 + 128 + c], (double)F3[nb + c], h);
    double y = sc * h + sh;
    y = y > 0.0 ? y : 0.2 * y;
    mx = fmax(mx, y);
  }
  redm[g][o] = mx;
  __syncthreads();
  if (t < 64) {
    double m = fmax(fmax(redm[0][o], redm[1][o]), fmax(redm[2][o], redm[3][o]));
    out[(size_t)b * OUTC + o0 + o] = (float)m;
  }
}

extern "C" void kernel_launch(void* const* d_in, const int* in_sizes, int n_in,
                              void* d_out, int out_size, void* d_ws, size_t ws_size,
                              hipStream_t stream) {
  (void)in_sizes; (void)n_in; (void)out_size; (void)ws_size;
  const float* x  = (const float*)d_in[0];
  const float* W1 = (const float*)d_in[1];
  const float* g1 = (const float*)d_in[2];
  const float* b1 = (const float*)d_in[3];
  const float* W2 = (const float*)d_in[4];
  const float* g2 = (const float*)d_in[5];
  const float* b2 = (const float*)d_in[6];
  const float* W3 = (const float*)d_in[7];
  const float* g3 = (const float*)d_in[8];
  const float* b3 = (const float*)d_in[9];
  const float* Wf = (const float*)d_in[10];
  const float* gf = (const float*)d_in[11];
  const float* bf = (const float*)d_in[12];
  float* out = (float*)d_out;

  char* wsb = (char*)d_ws;
  float* F1f    = (float*)(wsb + 0);           // 8 MB
  float* F2f    = (float*)(wsb + 8388608);     // 8 MB
  float* F3f    = (float*)(wsb + 16777216);    // 8 MB
  float* xxf    = (float*)(wsb + 25165824);    // 128 KB
  int* idx      = (int*)(wsb + 25296896);      // 2.62 MB
  double* sumsd = (double*)(wsb + 27918336);   // 128 doubles
  double* fsums = (double*)(wsb + 27920384);   // 2048 doubles
  double* fscsh = (double*)(wsb + 27936768);   // 2048 doubles
  float* mrs    = (float*)(wsb + 27953152);    // 128 floats

  const float* Fin[3] = {x, F1f, F2f};
  float* Fout[3] = {F1f, F2f, F3f};
  const float* Ws[3] = {W1, W2, W3};
  const float* gs[3] = {g1, g2, g3};
  const float* bs[3] = {b1, b2, b3};

  for (int L = 0; L < 3; ++L) {
    xx32_kernel<<<dim3(BB * NN / 256), 256, 0, stream>>>(Fin[L], xxf);
    knn32_kernel<<<dim3(NN / 64, BB), 64, 0, stream>>>(Fin[L], xxf, idx);
    hipMemsetAsync(sumsd, 0, 128 * sizeof(double), stream);
    stats_np<<<dim3(NN / 64, BB), 256, 0, stream>>>(Fin[L], Ws[L], idx, sumsd);
    finalize_np<<<1, 64, 0, stream>>>(sumsd, 1.0 / (double)(BB * NN * KNN), mrs);
    apply_np<<<dim3(NN / 64, BB), 256, 0, stream>>>(Fin[L], Ws[L], idx, mrs,
                                                    gs[L], bs[L], Fout[L]);
  }
  hipMemsetAsync(fsums, 0, 2048 * sizeof(double), stream);
  fstats_bf<<<dim3(OUTC / 64, BB), 256, 0, stream>>>(F1f, F2f, F3f, Wf, fsums);
  finalize_d<<<4, 256, 0, stream>>>(fsums, gf, bf, 1.0 / (double)(BB * NN),
                                    1024, 1024, fscsh);
  fapply_bf<<<dim3(OUTC / 64, BB), 256, 0, stream>>>(F1f, F2f, F3f, Wf, fscsh, out);
}

// Round 9
// 23822.272 us; speedup vs baseline: 1.0303x; 1.0303x over previous
//
#include <hip/hip_runtime.h>

#define BB 16
#define NN 2048
#define CC 64
#define KNN 20
#define OUTC 1024

// ====== xx: numpy pairwise_sum(n=64, 8-acc path) over RN(f^2) ======
__global__ __launch_bounds__(256) void xx32_kernel(const float* __restrict__ F,
                                                   float* __restrict__ xxf) {
  int p = blockIdx.x * 256 + threadIdx.x;
  const float* f = F + (size_t)p * CC;
  float t[64];
#pragma unroll
  for (int c = 0; c < 64; ++c) t[c] = f[c] * f[c];
  float r[8];
#pragma unroll
  for (int j = 0; j < 8; ++j) r[j] = t[j];
#pragma unroll
  for (int i = 8; i < 64; i += 8)
#pragma unroll
    for (int j = 0; j < 8; ++j) r[j] += t[i + j];
  float res = ((r[0] + r[1]) + (r[2] + r[3])) + ((r[4] + r[5]) + (r[6] + r[7]));
  xxf[p] = res;
}

// ====== packed top-k key: monotone f32 score (hi) | inverted index (lo) ======
// strict > on key == (score, -m) lexicographic: tie -> lower index.
__device__ __forceinline__ unsigned long long packkey(float s, int m) {
  unsigned int u = __float_as_uint(s);
  u ^= (u >> 31) ? 0xFFFFFFFFu : 0x80000000u;
  return ((unsigned long long)u << 32) | (unsigned int)(NN - 1 - m);
}

#define INSERT_KEY(key)                                   \
  if ((key) > kv[KNN - 1]) {                              \
    _Pragma("unroll")                                     \
    for (int jj = KNN - 1; jj >= 1; --jj) {               \
      if ((key) > kv[jj - 1]) kv[jj] = kv[jj - 1];        \
      else if ((key) > kv[jj]) kv[jj] = (key);            \
    }                                                     \
    if ((key) > kv[0]) kv[0] = (key);                     \
  }

// ====== kNN: tiled gram (BLAS seq-ascending f32 chain per pair) + insertion top-k ======
// LDS: SQc/SPc transposed f32[c][68], SS f32[row][68], xq/xp; merge overlays front.
__global__ __launch_bounds__(256) void knn_fast(const float* __restrict__ F,
                                                const float* __restrict__ xxf,
                                                int* __restrict__ idx) {
  __shared__ __align__(16) char smem[52736];
  float* SQc = (float*)smem;                  // [64 c][68] = 17408 B
  float* SPc = (float*)(smem + 17408);        // 17408 B
  float* SS  = (float*)(smem + 34816);        // [64 row][68] = 17408 B
  float* xq  = (float*)(smem + 52224);        // 64
  float* xp  = (float*)(smem + 52480);        // 64

  int b = blockIdx.y, n0 = blockIdx.x * 64, t = threadIdx.x;
  const float* fb = F + (size_t)b * NN * CC;

  // stage queries transposed
#pragma unroll
  for (int j = 0; j < 4; ++j) {
    int v = t + 256 * j;
    int row = v >> 4, c4 = (v & 15) * 4;
    float4 val = *(const float4*)(fb + (size_t)(n0 + row) * CC + c4);
    SQc[(c4 + 0) * 68 + row] = val.x;
    SQc[(c4 + 1) * 68 + row] = val.y;
    SQc[(c4 + 2) * 68 + row] = val.z;
    SQc[(c4 + 3) * 68 + row] = val.w;
  }
  if (t < 64) xq[t] = xxf[b * NN + n0 + t];

  unsigned long long kv[KNN];
#pragma unroll
  for (int k = 0; k < KNN; ++k) kv[k] = 0ull;

  int tx = t & 15, ty = t >> 4;  // gram: rows ty*4+i, cols tx*4+j
  int r = t & 63, qq = t >> 6;   // scan: row r, quarter qq

  for (int m0 = 0; m0 < NN; m0 += 64) {
    __syncthreads();  // prev scan done, SPc free
#pragma unroll
    for (int j = 0; j < 4; ++j) {
      int v = t + 256 * j;
      int row = v >> 4, c4 = (v & 15) * 4;
      float4 val = *(const float4*)(fb + (size_t)(m0 + row) * CC + c4);
      SPc[(c4 + 0) * 68 + row] = val.x;
      SPc[(c4 + 1) * 68 + row] = val.y;
      SPc[(c4 + 2) * 68 + row] = val.z;
      SPc[(c4 + 3) * 68 + row] = val.w;
    }
    if (t < 64) xp[t] = xxf[b * NN + m0 + t];
    __syncthreads();

    float acc[4][4] = {};
#pragma unroll 8
    for (int c = 0; c < 64; ++c) {  // ascending c: preserves BLAS chain per pair
      float4 av = *(const float4*)&SQc[c * 68 + ty * 4];
      float4 bv = *(const float4*)&SPc[c * 68 + tx * 4];
      float a[4] = {av.x, av.y, av.z, av.w};
      float bb4[4] = {bv.x, bv.y, bv.z, bv.w};
#pragma unroll
      for (int i = 0; i < 4; ++i)
#pragma unroll
        for (int j = 0; j < 4; ++j) acc[i][j] = fmaf(a[i], bb4[j], acc[i][j]);
    }
#pragma unroll
    for (int i = 0; i < 4; ++i) {
      float xn = xq[ty * 4 + i];
      float4 sv;
      sv.x = (2.0f * acc[i][0] - xn) - xp[tx * 4 + 0];
      sv.y = (2.0f * acc[i][1] - xn) - xp[tx * 4 + 1];
      sv.z = (2.0f * acc[i][2] - xn) - xp[tx * 4 + 2];
      sv.w = (2.0f * acc[i][3] - xn) - xp[tx * 4 + 3];
      *(float4*)&SS[(ty * 4 + i) * 68 + tx * 4] = sv;
    }
    __syncthreads();

#pragma unroll
    for (int j4 = 0; j4 < 4; ++j4) {
      float4 sv = *(const float4*)&SS[r * 68 + qq * 16 + j4 * 4];
      int mb = m0 + qq * 16 + j4 * 4;
      unsigned long long k0 = packkey(sv.x, mb + 0);
      INSERT_KEY(k0)
      unsigned long long k1 = packkey(sv.y, mb + 1);
      INSERT_KEY(k1)
      unsigned long long k2 = packkey(sv.z, mb + 2);
      INSERT_KEY(k2)
      unsigned long long k3 = packkey(sv.w, mb + 3);
      INSERT_KEY(k3)
    }
  }

  // merge 4 quarter-lists per row
  __syncthreads();
  unsigned long long* keys = (unsigned long long*)smem;  // 256*20*8 = 40960 B
#pragma unroll
  for (int k = 0; k < KNN; ++k) keys[t * KNN + k] = kv[k];
  __syncthreads();
  if (t < 64) {
    for (int q2 = 1; q2 < 4; ++q2) {
      int base = (q2 * 64 + t) * KNN;
#pragma unroll 1
      for (int k = 0; k < KNN; ++k) {
        unsigned long long key = keys[base + k];
        if (key <= kv[KNN - 1]) break;
        INSERT_KEY(key)
      }
    }
    int* dst = idx + (size_t)(b * NN + n0 + t) * KNN;
#pragma unroll
    for (int k = 0; k < KNN; ++k)
      dst[k] = (NN - 1) - (int)(unsigned int)(kv[k] & 0xFFFFFFFFull);
  }
}

// ====== h chain: BLAS f32 seq ascending FMA over e=0..127 (bit-identical) ======
// ====== EdgeConv stats: f64 sums of f32 h, 2-way k unroll ======
__global__ __launch_bounds__(256) void stats_np(const float* __restrict__ F,
                                                const float* __restrict__ W,
                                                const int* __restrict__ idx,
                                                double* __restrict__ sums) {
  __shared__ float Wl[64 * 129];
  __shared__ float Fn[64 * 65];
  __shared__ double rs[256], rss[256];
  int b = blockIdx.y, n0 = blockIdx.x * 64, t = threadIdx.x;
  for (int j = 0; j < 32; ++j) {
    int v = t + 256 * j;
    int o = v >> 7, e = v & 127;
    Wl[o * 129 + e] = W[o * 128 + e];
  }
  for (int j = 0; j < 4; ++j) {
    int v = t + 256 * j;
    int row = v >> 4, c4 = (v & 15) * 4;
    float4 val = *(const float4*)(F + ((size_t)(b * NN + n0 + row)) * CC + c4);
    Fn[row * 65 + c4] = val.x; Fn[row * 65 + c4 + 1] = val.y;
    Fn[row * 65 + c4 + 2] = val.z; Fn[row * 65 + c4 + 3] = val.w;
  }
  __syncthreads();
  int o = t & 63, g4 = t >> 6;
  const float* wo = &Wl[o * 129];
  double s = 0.0, ss = 0.0;
  for (int i = 0; i < 16; ++i) {
    int n = n0 + g4 * 16 + i;
    const float* fnp = &Fn[(g4 * 16 + i) * 65];
    const int* ip = idx + ((size_t)(b * NN + n)) * KNN;
#pragma unroll 1
    for (int k = 0; k < KNN; k += 2) {
      const float* fp0 = F + ((size_t)(b * NN + ip[k])) * CC;
      const float* fp1 = F + ((size_t)(b * NN + ip[k + 1])) * CC;
      float fm0[64], fm1[64];
#pragma unroll
      for (int c4 = 0; c4 < 16; ++c4) {
        *(float4*)&fm0[c4 * 4] = *(const float4*)(fp0 + c4 * 4);
        *(float4*)&fm1[c4 * 4] = *(const float4*)(fp1 + c4 * 4);
      }
      float a0 = 0.f, a1 = 0.f;
#pragma unroll
      for (int c = 0; c < 64; ++c) {
        float fn = fnp[c], w = wo[c];
        a0 = fmaf(w, fm0[c] - fn, a0);
        a1 = fmaf(w, fm1[c] - fn, a1);
      }
#pragma unroll
      for (int c = 0; c < 64; ++c) {
        float fn = fnp[c], w = wo[64 + c];
        a0 = fmaf(w, fn, a0);
        a1 = fmaf(w, fn, a1);
      }
      s += (double)a0 + (double)a1;
      ss += (double)a0 * (double)a0 + (double)a1 * (double)a1;
    }
  }
  rs[t] = s; rss[t] = ss;
  __syncthreads();
  if (t < 64) {
    double a = rs[t] + rs[t + 64] + rs[t + 128] + rs[t + 192];
    double q = rss[t] + rss[t + 64] + rss[t + 128] + rss[t + 192];
    atomicAdd(&sums[o], a);
    atomicAdd(&sums[64 + o], q);
  }
}

// ====== BN finalize for edge layers: f32 mean + f32 rs (unchanged numerics) ======
__global__ void finalize_np(const double* __restrict__ sums, double cntinv,
                            float* __restrict__ mrs) {
  int c = threadIdx.x;  // 64
  double mean = sums[c] * cntinv;
  double var = sums[64 + c] * cntinv - mean * mean;
  mrs[c] = (float)mean;
  mrs[64 + c] = 1.0f / sqrtf((float)var + 1e-5f);
}

// ====== EdgeConv apply: f32 h chain + normalize chain + max_k, 2-way k unroll ======
__global__ __launch_bounds__(256) void apply_np(const float* __restrict__ F,
                                                const float* __restrict__ W,
                                                const int* __restrict__ idx,
                                                const float* __restrict__ mrs,
                                                const float* __restrict__ gv,
                                                const float* __restrict__ bv,
                                                float* __restrict__ Fo) {
  __shared__ float Wl[64 * 129];
  __shared__ float Fn[64 * 65];
  int b = blockIdx.y, n0 = blockIdx.x * 64, t = threadIdx.x;
  for (int j = 0; j < 32; ++j) {
    int v = t + 256 * j;
    int o = v >> 7, e = v & 127;
    Wl[o * 129 + e] = W[o * 128 + e];
  }
  for (int j = 0; j < 4; ++j) {
    int v = t + 256 * j;
    int row = v >> 4, c4 = (v & 15) * 4;
    float4 val = *(const float4*)(F + ((size_t)(b * NN + n0 + row)) * CC + c4);
    Fn[row * 65 + c4] = val.x; Fn[row * 65 + c4 + 1] = val.y;
    Fn[row * 65 + c4 + 2] = val.z; Fn[row * 65 + c4 + 3] = val.w;
  }
  __syncthreads();
  int o = t & 63, g4 = t >> 6;
  float m32 = mrs[o], rs32 = mrs[64 + o];
  float gg = gv[o], bb = bv[o];
  const float* wo = &Wl[o * 129];
  for (int i = 0; i < 16; ++i) {
    int n = n0 + g4 * 16 + i;
    const float* fnp = &Fn[(g4 * 16 + i) * 65];
    const int* ip = idx + ((size_t)(b * NN + n)) * KNN;
    float mx = -3.0e38f;
#pragma unroll 1
    for (int k = 0; k < KNN; k += 2) {
      const float* fp0 = F + ((size_t)(b * NN + ip[k])) * CC;
      const float* fp1 = F + ((size_t)(b * NN + ip[k + 1])) * CC;
      float fm0[64], fm1[64];
#pragma unroll
      for (int c4 = 0; c4 < 16; ++c4) {
        *(float4*)&fm0[c4 * 4] = *(const float4*)(fp0 + c4 * 4);
        *(float4*)&fm1[c4 * 4] = *(const float4*)(fp1 + c4 * 4);
      }
      float a0 = 0.f, a1 = 0.f;
#pragma unroll
      for (int c = 0; c < 64; ++c) {
        float fn = fnp[c], w = wo[c];
        a0 = fmaf(w, fm0[c] - fn, a0);
        a1 = fmaf(w, fm1[c] - fn, a1);
      }
#pragma unroll
      for (int c = 0; c < 64; ++c) {
        float fn = fnp[c], w = wo[64 + c];
        a0 = fmaf(w, fn, a0);
        a1 = fmaf(w, fn, a1);
      }
      float d0 = a0 - m32; d0 = d0 * rs32; d0 = d0 * gg;
      float y0 = d0 + bb;
      y0 = y0 >= 0.f ? y0 : 0.2f * y0;
      float d1 = a1 - m32; d1 = d1 * rs32; d1 = d1 * gg;
      float y1 = d1 + bb;
      y1 = y1 >= 0.f ? y1 : 0.2f * y1;
      mx = fmaxf(mx, fmaxf(y0, y1));
    }
    Fo[((size_t)(b * NN + n)) * CC + o] = mx;
  }
}

// ====== final projection stats: f32 BLAS chain, 4-row ILP, f64 sums ======
__global__ __launch_bounds__(256) void fstats32(const float* __restrict__ F1,
                                                const float* __restrict__ F2,
                                                const float* __restrict__ F3,
                                                const float* __restrict__ Wf,
                                                double* __restrict__ sums) {
  __shared__ float Wl[64 * 193];
  __shared__ double rs[256], rss[256];
  int b = blockIdx.y, o0 = blockIdx.x * 64, t = threadIdx.x;
  for (int j = 0; j < 48; ++j) {
    int v = t + 256 * j;
    int oo = v / 192, c = v - oo * 192;
    Wl[oo * 193 + c] = Wf[(size_t)(o0 + oo) * 192 + c];
  }
  __syncthreads();
  int o = t & 63, g = t >> 6;
  const float* fs[3] = {F1, F2, F3};
  double s = 0.0, ss = 0.0;
  for (int n0 = 0; n0 < NN; n0 += 16) {
    int n = n0 + g * 4;
    float h[4] = {0.f, 0.f, 0.f, 0.f};
#pragma unroll
    for (int part = 0; part < 3; ++part) {
      const float* src = fs[part] + ((size_t)(b * NN + n)) * CC;
      const float* wp = &Wl[o * 193 + part * 64];
#pragma unroll 4
      for (int c4 = 0; c4 < 16; ++c4) {
        float4 w4 = {wp[c4 * 4], wp[c4 * 4 + 1], wp[c4 * 4 + 2], wp[c4 * 4 + 3]};
#pragma unroll
        for (int i = 0; i < 4; ++i) {
          float4 v = *(const float4*)(src + (size_t)i * CC + c4 * 4);
          h[i] = fmaf(w4.x, v.x, h[i]);
          h[i] = fmaf(w4.y, v.y, h[i]);
          h[i] = fmaf(w4.z, v.z, h[i]);
          h[i] = fmaf(w4.w, v.w, h[i]);
        }
      }
    }
#pragma unroll
    for (int i = 0; i < 4; ++i) {
      s += (double)h[i];
      ss += (double)h[i] * (double)h[i];
    }
  }
  rs[t] = s; rss[t] = ss;
  __syncthreads();
  if (t < 64) {
    double a = rs[t] + rs[t + 64] + rs[t + 128] + rs[t + 192];
    double q = rss[t] + rss[t + 64] + rss[t + 128] + rss[t + 192];
    atomicAdd(&sums[o0 + o], a);
    atomicAdd(&sums[1024 + o0 + o], q);
  }
}

// ====== BN finalize (final layer): f64 math -> f32 sc/sh ======
__global__ void finalize_f(const double* __restrict__ sums,
                           const float* __restrict__ g,
                           const float* __restrict__ bb, double cntinv,
                           float* __restrict__ scsh) {
  int c = blockIdx.x * 256 + threadIdx.x;  // 1024
  double mean = sums[c] * cntinv;
  double var = sums[1024 + c] * cntinv - mean * mean;
  double sc = (double)g[c] / sqrt(var + 1e-5);
  scsh[c] = (float)sc;
  scsh[1024 + c] = (float)((double)bb[c] - mean * sc);
}

// ====== final apply: f32 chain, 4-row ILP, max over n ======
__global__ __launch_bounds__(256) void fapply32(const float* __restrict__ F1,
                                                const float* __restrict__ F2,
                                                const float* __restrict__ F3,
                                                const float* __restrict__ Wf,
                                                const float* __restrict__ scsh,
                                                float* __restrict__ out) {
  __shared__ float Wl[64 * 193];
  __shared__ float redm[4][64];
  int b = blockIdx.y, o0 = blockIdx.x * 64, t = threadIdx.x;
  for (int j = 0; j < 48; ++j) {
    int v = t + 256 * j;
    int oo = v / 192, c = v - oo * 192;
    Wl[oo * 193 + c] = Wf[(size_t)(o0 + oo) * 192 + c];
  }
  __syncthreads();
  int o = t & 63, g = t >> 6;
  float sc = scsh[o0 + o], sh = scsh[1024 + o0 + o];
  const float* fs[3] = {F1, F2, F3};
  float mx = -3.0e38f;
  for (int n0 = 0; n0 < NN; n0 += 16) {
    int n = n0 + g * 4;
    float h[4] = {0.f, 0.f, 0.f, 0.f};
#pragma unroll
    for (int part = 0; part < 3; ++part) {
      const float* src = fs[part] + ((size_t)(b * NN + n)) * CC;
      const float* wp = &Wl[o * 193 + part * 64];
#pragma unroll 4
      for (int c4 = 0; c4 < 16; ++c4) {
        float4 w4 = {wp[c4 * 4], wp[c4 * 4 + 1], wp[c4 * 4 + 2], wp[c4 * 4 + 3]};
#pragma unroll
        for (int i = 0; i < 4; ++i) {
          float4 v = *(const float4*)(src + (size_t)i * CC + c4 * 4);
          h[i] = fmaf(w4.x, v.x, h[i]);
          h[i] = fmaf(w4.y, v.y, h[i]);
          h[i] = fmaf(w4.z, v.z, h[i]);
          h[i] = fmaf(w4.w, v.w, h[i]);
        }
      }
    }
#pragma unroll
    for (int i = 0; i < 4; ++i) {
      float y = fmaf(sc, h[i], sh);
      y = y >= 0.f ? y : 0.2f * y;
      mx = fmaxf(mx, y);
    }
  }
  redm[g][o] = mx;
  __syncthreads();
  if (t < 64) {
    float m = fmaxf(fmaxf(redm[0][o], redm[1][o]), fmaxf(redm[2][o], redm[3][o]));
    out[(size_t)b * OUTC + o0 + o] = m;
  }
}

extern "C" void kernel_launch(void* const* d_in, const int* in_sizes, int n_in,
                              void* d_out, int out_size, void* d_ws, size_t ws_size,
                              hipStream_t stream) {
  (void)in_sizes; (void)n_in; (void)out_size; (void)ws_size;
  const float* x  = (const float*)d_in[0];
  const float* W1 = (const float*)d_in[1];
  const float* g1 = (const float*)d_in[2];
  const float* b1 = (const float*)d_in[3];
  const float* W2 = (const float*)d_in[4];
  const float* g2 = (const float*)d_in[5];
  const float* b2 = (const float*)d_in[6];
  const float* W3 = (const float*)d_in[7];
  const float* g3 = (const float*)d_in[8];
  const float* b3 = (const float*)d_in[9];
  const float* Wf = (const float*)d_in[10];
  const float* gf = (const float*)d_in[11];
  const float* bf = (const float*)d_in[12];
  float* out = (float*)d_out;

  char* wsb = (char*)d_ws;
  float* F1f    = (float*)(wsb + 0);           // 8 MB
  float* F2f    = (float*)(wsb + 8388608);     // 8 MB
  float* F3f    = (float*)(wsb + 16777216);    // 8 MB
  float* xxf    = (float*)(wsb + 25165824);    // 128 KB
  int* idx      = (int*)(wsb + 25296896);      // 2.62 MB
  double* sumsd = (double*)(wsb + 27918336);   // 128 doubles
  double* fsums = (double*)(wsb + 27920384);   // 2048 doubles
  float* fscsh  = (float*)(wsb + 27936768);    // 2048 floats
  float* mrs    = (float*)(wsb + 27944960);    // 128 floats

  const float* Fin[3] = {x, F1f, F2f};
  float* Fout[3] = {F1f, F2f, F3f};
  const float* Ws[3] = {W1, W2, W3};
  const float* gs[3] = {g1, g2, g3};
  const float* bs[3] = {b1, b2, b3};

  for (int L = 0; L < 3; ++L) {
    xx32_kernel<<<dim3(BB * NN / 256), 256, 0, stream>>>(Fin[L], xxf);
    knn_fast<<<dim3(NN / 64, BB), 256, 0, stream>>>(Fin[L], xxf, idx);
    hipMemsetAsync(sumsd, 0, 128 * sizeof(double), stream);
    stats_np<<<dim3(NN / 64, BB), 256, 0, stream>>>(Fin[L], Ws[L], idx, sumsd);
    finalize_np<<<1, 64, 0, stream>>>(sumsd, 1.0 / (double)(BB * NN * KNN), mrs);
    apply_np<<<dim3(NN / 64, BB), 256, 0, stream>>>(Fin[L], Ws[L], idx, mrs,
                                                    gs[L], bs[L], Fout[L]);
  }
  hipMemsetAsync(fsums, 0, 2048 * sizeof(double), stream);
  fstats32<<<dim3(OUTC / 64, BB), 256, 0, stream>>>(F1f, F2f, F3f, Wf, fsums);
  finalize_f<<<4, 256, 0, stream>>>(fsums, gf, bf, 1.0 / (double)(BB * NN), fscsh);
  fapply32<<<dim3(OUTC / 64, BB), 256, 0, stream>>>(F1f, F2f, F3f, Wf, fscsh, out);
}

// Round 10
// 3726.329 us; speedup vs baseline: 6.5865x; 6.3930x over previous
//
#include <hip/hip_runtime.h>

#define BB 16
#define NN 2048
#define CC 64
#define KNN 20
#define OUTC 1024

// ====== xx: numpy pairwise_sum(n=64, 8-acc path) over RN(f^2) ======
__global__ __launch_bounds__(256) void xx32_kernel(const float* __restrict__ F,
                                                   float* __restrict__ xxf) {
  int p = blockIdx.x * 256 + threadIdx.x;
  const float* f = F + (size_t)p * CC;
  float t[64];
#pragma unroll
  for (int c = 0; c < 64; ++c) t[c] = f[c] * f[c];
  float r[8];
#pragma unroll
  for (int j = 0; j < 8; ++j) r[j] = t[j];
#pragma unroll
  for (int i = 8; i < 64; i += 8)
#pragma unroll
    for (int j = 0; j < 8; ++j) r[j] += t[i + j];
  float res = ((r[0] + r[1]) + (r[2] + r[3])) + ((r[4] + r[5]) + (r[6] + r[7]));
  xxf[p] = res;
}

// ====== packed top-k key: monotone f32 score (hi) | inverted index (lo) ======
__device__ __forceinline__ unsigned long long packkey(float s, int m) {
  unsigned int u = __float_as_uint(s);
  u ^= (u >> 31) ? 0xFFFFFFFFu : 0x80000000u;
  return ((unsigned long long)u << 32) | (unsigned int)(NN - 1 - m);
}

#define INSERT_KEY(key)                                   \
  if ((key) > kv[KNN - 1]) {                              \
    _Pragma("unroll")                                     \
    for (int jj = KNN - 1; jj >= 1; --jj) {               \
      if ((key) > kv[jj - 1]) kv[jj] = kv[jj - 1];        \
      else if ((key) > kv[jj]) kv[jj] = (key);            \
    }                                                     \
    if ((key) > kv[0]) kv[0] = (key);                     \
  }

// ====== kNN: tiled gram (BLAS seq-ascending f32 chain per pair) + insertion top-k ======
__global__ __launch_bounds__(256) void knn_fast(const float* __restrict__ F,
                                                const float* __restrict__ xxf,
                                                int* __restrict__ idx) {
  __shared__ __align__(16) char smem[52736];
  float* SQc = (float*)smem;                  // [64 c][68]
  float* SPc = (float*)(smem + 17408);
  float* SS  = (float*)(smem + 34816);        // [64 row][68]
  float* xq  = (float*)(smem + 52224);
  float* xp  = (float*)(smem + 52480);

  int b = blockIdx.y, n0 = blockIdx.x * 64, t = threadIdx.x;
  const float* fb = F + (size_t)b * NN * CC;

#pragma unroll
  for (int j = 0; j < 4; ++j) {
    int v = t + 256 * j;
    int row = v >> 4, c4 = (v & 15) * 4;
    float4 val = *(const float4*)(fb + (size_t)(n0 + row) * CC + c4);
    SQc[(c4 + 0) * 68 + row] = val.x;
    SQc[(c4 + 1) * 68 + row] = val.y;
    SQc[(c4 + 2) * 68 + row] = val.z;
    SQc[(c4 + 3) * 68 + row] = val.w;
  }
  if (t < 64) xq[t] = xxf[b * NN + n0 + t];

  unsigned long long kv[KNN];
#pragma unroll
  for (int k = 0; k < KNN; ++k) kv[k] = 0ull;

  int tx = t & 15, ty = t >> 4;
  int r = t & 63, qq = t >> 6;

  for (int m0 = 0; m0 < NN; m0 += 64) {
    __syncthreads();
#pragma unroll
    for (int j = 0; j < 4; ++j) {
      int v = t + 256 * j;
      int row = v >> 4, c4 = (v & 15) * 4;
      float4 val = *(const float4*)(fb + (size_t)(m0 + row) * CC + c4);
      SPc[(c4 + 0) * 68 + row] = val.x;
      SPc[(c4 + 1) * 68 + row] = val.y;
      SPc[(c4 + 2) * 68 + row] = val.z;
      SPc[(c4 + 3) * 68 + row] = val.w;
    }
    if (t < 64) xp[t] = xxf[b * NN + m0 + t];
    __syncthreads();

    float acc[4][4] = {};
#pragma unroll 8
    for (int c = 0; c < 64; ++c) {
      float4 av = *(const float4*)&SQc[c * 68 + ty * 4];
      float4 bv = *(const float4*)&SPc[c * 68 + tx * 4];
      float a[4] = {av.x, av.y, av.z, av.w};
      float bb4[4] = {bv.x, bv.y, bv.z, bv.w};
#pragma unroll
      for (int i = 0; i < 4; ++i)
#pragma unroll
        for (int j = 0; j < 4; ++j) acc[i][j] = fmaf(a[i], bb4[j], acc[i][j]);
    }
#pragma unroll
    for (int i = 0; i < 4; ++i) {
      float xn = xq[ty * 4 + i];
      float4 sv;
      sv.x = (2.0f * acc[i][0] - xn) - xp[tx * 4 + 0];
      sv.y = (2.0f * acc[i][1] - xn) - xp[tx * 4 + 1];
      sv.z = (2.0f * acc[i][2] - xn) - xp[tx * 4 + 2];
      sv.w = (2.0f * acc[i][3] - xn) - xp[tx * 4 + 3];
      *(float4*)&SS[(ty * 4 + i) * 68 + tx * 4] = sv;
    }
    __syncthreads();

#pragma unroll
    for (int j4 = 0; j4 < 4; ++j4) {
      float4 sv = *(const float4*)&SS[r * 68 + qq * 16 + j4 * 4];
      int mb = m0 + qq * 16 + j4 * 4;
      unsigned long long k0 = packkey(sv.x, mb + 0);
      INSERT_KEY(k0)
      unsigned long long k1 = packkey(sv.y, mb + 1);
      INSERT_KEY(k1)
      unsigned long long k2 = packkey(sv.z, mb + 2);
      INSERT_KEY(k2)
      unsigned long long k3 = packkey(sv.w, mb + 3);
      INSERT_KEY(k3)
    }
  }

  __syncthreads();
  unsigned long long* keys = (unsigned long long*)smem;
#pragma unroll
  for (int k = 0; k < KNN; ++k) keys[t * KNN + k] = kv[k];
  __syncthreads();
  if (t < 64) {
    for (int q2 = 1; q2 < 4; ++q2) {
      int base = (q2 * 64 + t) * KNN;
#pragma unroll 1
      for (int k = 0; k < KNN; ++k) {
        unsigned long long key = keys[base + k];
        if (key <= kv[KNN - 1]) break;
        INSERT_KEY(key)
      }
    }
    int* dst = idx + (size_t)(b * NN + n0 + t) * KNN;
#pragma unroll
    for (int k = 0; k < KNN; ++k)
      dst[k] = (NN - 1) - (int)(unsigned int)(kv[k] & 0xFFFFFFFFull);
  }
}

// ====== EdgeConv stats: register-cached w, wave-uniform fm streams, optional h cache ======
// h chain per (n,k,o): f32 seq ascending FMA over e=0..127 — BIT-IDENTICAL contract.
template <int CACHE>
__global__ __launch_bounds__(256) void stats_k(const float* __restrict__ F,
                                               const float* __restrict__ W,
                                               const int* __restrict__ idx,
                                               double* __restrict__ sums,
                                               float* __restrict__ hout) {
  __shared__ float Fn[64 * 64];
  __shared__ double rs[256], rss[256];
  int b = blockIdx.y, n0 = blockIdx.x * 64, t = threadIdx.x;
  int o = t & 63, g4 = t >> 6;
#pragma unroll
  for (int j = 0; j < 4; ++j) {
    int v = t + 256 * j;
    int row = v >> 4, c4 = (v & 15) * 4;
    *(float4*)&Fn[row * 64 + c4] =
        *(const float4*)(F + ((size_t)(b * NN + n0 + row)) * CC + c4);
  }
  float4 w0[16], w1[16];
  const float* wp = W + o * 128;
#pragma unroll
  for (int c4 = 0; c4 < 16; ++c4) {
    w0[c4] = *(const float4*)(wp + c4 * 4);
    w1[c4] = *(const float4*)(wp + 64 + c4 * 4);
  }
  __syncthreads();
  double s = 0.0, ss = 0.0;
  for (int i = 0; i < 16; ++i) {
    int n = n0 + g4 * 16 + i;
    float4 fn[16];
#pragma unroll
    for (int c4 = 0; c4 < 16; ++c4) fn[c4] = *(float4*)&Fn[(g4 * 16 + i) * 64 + c4 * 4];
    const int* ip = idx + ((size_t)(b * NN + n)) * KNN;
#pragma unroll 1
    for (int k = 0; k < KNN; k += 2) {
      const float* fp0 = F + ((size_t)(b * NN + ip[k])) * CC;
      const float* fp1 = F + ((size_t)(b * NN + ip[k + 1])) * CC;
      float a0 = 0.f, a1 = 0.f;
#pragma unroll
      for (int c4 = 0; c4 < 16; ++c4) {
        float4 f0 = *(const float4*)(fp0 + c4 * 4);
        float4 f1 = *(const float4*)(fp1 + c4 * 4);
        float4 fv = fn[c4], wv = w0[c4];
        a0 = fmaf(wv.x, f0.x - fv.x, a0);
        a0 = fmaf(wv.y, f0.y - fv.y, a0);
        a0 = fmaf(wv.z, f0.z - fv.z, a0);
        a0 = fmaf(wv.w, f0.w - fv.w, a0);
        a1 = fmaf(wv.x, f1.x - fv.x, a1);
        a1 = fmaf(wv.y, f1.y - fv.y, a1);
        a1 = fmaf(wv.z, f1.z - fv.z, a1);
        a1 = fmaf(wv.w, f1.w - fv.w, a1);
      }
#pragma unroll
      for (int c4 = 0; c4 < 16; ++c4) {
        float4 fv = fn[c4], wv = w1[c4];
        a0 = fmaf(wv.x, fv.x, a0);
        a0 = fmaf(wv.y, fv.y, a0);
        a0 = fmaf(wv.z, fv.z, a0);
        a0 = fmaf(wv.w, fv.w, a0);
        a1 = fmaf(wv.x, fv.x, a1);
        a1 = fmaf(wv.y, fv.y, a1);
        a1 = fmaf(wv.z, fv.z, a1);
        a1 = fmaf(wv.w, fv.w, a1);
      }
      s += (double)a0 + (double)a1;
      ss += (double)a0 * (double)a0 + (double)a1 * (double)a1;
      if (CACHE) {
        float* hp = hout + (((size_t)(b * NN + n)) * KNN + k) * 64 + o;
        hp[0] = a0;
        hp[64] = a1;
      }
    }
  }
  rs[t] = s; rss[t] = ss;
  __syncthreads();
  if (t < 64) {
    double a = rs[t] + rs[t + 64] + rs[t + 128] + rs[t + 192];
    double q = rss[t] + rss[t + 64] + rss[t + 128] + rss[t + 192];
    atomicAdd(&sums[o], a);
    atomicAdd(&sums[64 + o], q);
  }
}

// ====== BN finalize for edge layers: f32 mean + f32 rs ======
__global__ void finalize_np(const double* __restrict__ sums, double cntinv,
                            float* __restrict__ mrs) {
  int c = threadIdx.x;  // 64
  double mean = sums[c] * cntinv;
  double var = sums[64 + c] * cntinv - mean * mean;
  mrs[c] = (float)mean;
  mrs[64 + c] = 1.0f / sqrtf((float)var + 1e-5f);
}

// ====== apply (cached h): streaming normalize + max over k ======
__global__ __launch_bounds__(256) void apply_cached(const float* __restrict__ hin,
                                                    const float* __restrict__ mrs,
                                                    const float* __restrict__ gv,
                                                    const float* __restrict__ bvv,
                                                    float* __restrict__ Fo) {
  int t = threadIdx.x;
  int o = t & 63, ng = t >> 6;
  size_t n = (size_t)blockIdx.x * 4 + ng;  // flat (b*NN+n)
  const float* hp = hin + n * KNN * 64 + o;
  float m32 = mrs[o], rs32 = mrs[64 + o];
  float gg = gv[o], bb = bvv[o];
  float mx = -3.0e38f;
#pragma unroll
  for (int k = 0; k < KNN; ++k) {
    float h = hp[k * 64];
    float d = h - m32;
    d = d * rs32;
    d = d * gg;
    float y = d + bb;
    y = y >= 0.f ? y : 0.2f * y;
    mx = fmaxf(mx, y);
  }
  Fo[n * 64 + o] = mx;
}

// ====== apply (recompute fallback): same chain as stats_k + normalize + max ======
__global__ __launch_bounds__(256) void apply_rec(const float* __restrict__ F,
                                                 const float* __restrict__ W,
                                                 const int* __restrict__ idx,
                                                 const float* __restrict__ mrs,
                                                 const float* __restrict__ gv,
                                                 const float* __restrict__ bvv,
                                                 float* __restrict__ Fo) {
  __shared__ float Fn[64 * 64];
  int b = blockIdx.y, n0 = blockIdx.x * 64, t = threadIdx.x;
  int o = t & 63, g4 = t >> 6;
#pragma unroll
  for (int j = 0; j < 4; ++j) {
    int v = t + 256 * j;
    int row = v >> 4, c4 = (v & 15) * 4;
    *(float4*)&Fn[row * 64 + c4] =
        *(const float4*)(F + ((size_t)(b * NN + n0 + row)) * CC + c4);
  }
  float4 w0[16], w1[16];
  const float* wp = W + o * 128;
#pragma unroll
  for (int c4 = 0; c4 < 16; ++c4) {
    w0[c4] = *(const float4*)(wp + c4 * 4);
    w1[c4] = *(const float4*)(wp + 64 + c4 * 4);
  }
  __syncthreads();
  float m32 = mrs[o], rs32 = mrs[64 + o];
  float gg = gv[o], bb = bvv[o];
  for (int i = 0; i < 16; ++i) {
    int n = n0 + g4 * 16 + i;
    float4 fn[16];
#pragma unroll
    for (int c4 = 0; c4 < 16; ++c4) fn[c4] = *(float4*)&Fn[(g4 * 16 + i) * 64 + c4 * 4];
    const int* ip = idx + ((size_t)(b * NN + n)) * KNN;
    float mx = -3.0e38f;
#pragma unroll 1
    for (int k = 0; k < KNN; k += 2) {
      const float* fp0 = F + ((size_t)(b * NN + ip[k])) * CC;
      const float* fp1 = F + ((size_t)(b * NN + ip[k + 1])) * CC;
      float a0 = 0.f, a1 = 0.f;
#pragma unroll
      for (int c4 = 0; c4 < 16; ++c4) {
        float4 f0 = *(const float4*)(fp0 + c4 * 4);
        float4 f1 = *(const float4*)(fp1 + c4 * 4);
        float4 fv = fn[c4], wv = w0[c4];
        a0 = fmaf(wv.x, f0.x - fv.x, a0);
        a0 = fmaf(wv.y, f0.y - fv.y, a0);
        a0 = fmaf(wv.z, f0.z - fv.z, a0);
        a0 = fmaf(wv.w, f0.w - fv.w, a0);
        a1 = fmaf(wv.x, f1.x - fv.x, a1);
        a1 = fmaf(wv.y, f1.y - fv.y, a1);
        a1 = fmaf(wv.z, f1.z - fv.z, a1);
        a1 = fmaf(wv.w, f1.w - fv.w, a1);
      }
#pragma unroll
      for (int c4 = 0; c4 < 16; ++c4) {
        float4 fv = fn[c4], wv = w1[c4];
        a0 = fmaf(wv.x, fv.x, a0);
        a0 = fmaf(wv.y, fv.y, a0);
        a0 = fmaf(wv.z, fv.z, a0);
        a0 = fmaf(wv.w, fv.w, a0);
        a1 = fmaf(wv.x, fv.x, a1);
        a1 = fmaf(wv.y, fv.y, a1);
        a1 = fmaf(wv.z, fv.z, a1);
        a1 = fmaf(wv.w, fv.w, a1);
      }
      float d0 = a0 - m32; d0 = d0 * rs32; d0 = d0 * gg;
      float y0 = d0 + bb;
      y0 = y0 >= 0.f ? y0 : 0.2f * y0;
      float d1 = a1 - m32; d1 = d1 * rs32; d1 = d1 * gg;
      float y1 = d1 + bb;
      y1 = y1 >= 0.f ? y1 : 0.2f * y1;
      mx = fmaxf(mx, fmaxf(y0, y1));
    }
    Fo[((size_t)(b * NN + n)) * CC + o] = mx;
  }
}

// ====== final projection stats: f32 BLAS chain, 4-row ILP, f64 sums ======
__global__ __launch_bounds__(256) void fstats32(const float* __restrict__ F1,
                                                const float* __restrict__ F2,
                                                const float* __restrict__ F3,
                                                const float* __restrict__ Wf,
                                                double* __restrict__ sums) {
  __shared__ float Wl[64 * 193];
  __shared__ double rs[256], rss[256];
  int b = blockIdx.y, o0 = blockIdx.x * 64, t = threadIdx.x;
  for (int j = 0; j < 48; ++j) {
    int v = t + 256 * j;
    int oo = v / 192, c = v - oo * 192;
    Wl[oo * 193 + c] = Wf[(size_t)(o0 + oo) * 192 + c];
  }
  __syncthreads();
  int o = t & 63, g = t >> 6;
  const float* fs[3] = {F1, F2, F3};
  double s = 0.0, ss = 0.0;
  for (int n0 = 0; n0 < NN; n0 += 16) {
    int n = n0 + g * 4;
    float h[4] = {0.f, 0.f, 0.f, 0.f};
#pragma unroll
    for (int part = 0; part < 3; ++part) {
      const float* src = fs[part] + ((size_t)(b * NN + n)) * CC;
      const float* wp = &Wl[o * 193 + part * 64];
#pragma unroll 4
      for (int c4 = 0; c4 < 16; ++c4) {
        float4 w4 = {wp[c4 * 4], wp[c4 * 4 + 1], wp[c4 * 4 + 2], wp[c4 * 4 + 3]};
#pragma unroll
        for (int i = 0; i < 4; ++i) {
          float4 v = *(const float4*)(src + (size_t)i * CC + c4 * 4);
          h[i] = fmaf(w4.x, v.x, h[i]);
          h[i] = fmaf(w4.y, v.y, h[i]);
          h[i] = fmaf(w4.z, v.z, h[i]);
          h[i] = fmaf(w4.w, v.w, h[i]);
        }
      }
    }
#pragma unroll
    for (int i = 0; i < 4; ++i) {
      s += (double)h[i];
      ss += (double)h[i] * (double)h[i];
    }
  }
  rs[t] = s; rss[t] = ss;
  __syncthreads();
  if (t < 64) {
    double a = rs[t] + rs[t + 64] + rs[t + 128] + rs[t + 192];
    double q = rss[t] + rss[t + 64] + rss[t + 128] + rss[t + 192];
    atomicAdd(&sums[o0 + o], a);
    atomicAdd(&sums[1024 + o0 + o], q);
  }
}

// ====== BN finalize (final layer): f64 math -> f32 sc/sh ======
__global__ void finalize_f(const double* __restrict__ sums,
                           const float* __restrict__ g,
                           const float* __restrict__ bb, double cntinv,
                           float* __restrict__ scsh) {
  int c = blockIdx.x * 256 + threadIdx.x;  // 1024
  double mean = sums[c] * cntinv;
  double var = sums[1024 + c] * cntinv - mean * mean;
  double sc = (double)g[c] / sqrt(var + 1e-5);
  scsh[c] = (float)sc;
  scsh[1024 + c] = (float)((double)bb[c] - mean * sc);
}

// ====== final apply: f32 chain, 4-row ILP, max over n ======
__global__ __launch_bounds__(256) void fapply32(const float* __restrict__ F1,
                                                const float* __restrict__ F2,
                                                const float* __restrict__ F3,
                                                const float* __restrict__ Wf,
                                                const float* __restrict__ scsh,
                                                float* __restrict__ out) {
  __shared__ float Wl[64 * 193];
  __shared__ float redm[4][64];
  int b = blockIdx.y, o0 = blockIdx.x * 64, t = threadIdx.x;
  for (int j = 0; j < 48; ++j) {
    int v = t + 256 * j;
    int oo = v / 192, c = v - oo * 192;
    Wl[oo * 193 + c] = Wf[(size_t)(o0 + oo) * 192 + c];
  }
  __syncthreads();
  int o = t & 63, g = t >> 6;
  float sc = scsh[o0 + o], sh = scsh[1024 + o0 + o];
  const float* fs[3] = {F1, F2, F3};
  float mx = -3.0e38f;
  for (int n0 = 0; n0 < NN; n0 += 16) {
    int n = n0 + g * 4;
    float h[4] = {0.f, 0.f, 0.f, 0.f};
#pragma unroll
    for (int part = 0; part < 3; ++part) {
      const float* src = fs[part] + ((size_t)(b * NN + n)) * CC;
      const float* wp = &Wl[o * 193 + part * 64];
#pragma unroll 4
      for (int c4 = 0; c4 < 16; ++c4) {
        float4 w4 = {wp[c4 * 4], wp[c4 * 4 + 1], wp[c4 * 4 + 2], wp[c4 * 4 + 3]};
#pragma unroll
        for (int i = 0; i < 4; ++i) {
          float4 v = *(const float4*)(src + (size_t)i * CC + c4 * 4);
          h[i] = fmaf(w4.x, v.x, h[i]);
          h[i] = fmaf(w4.y, v.y, h[i]);
          h[i] = fmaf(w4.z, v.z, h[i]);
          h[i] = fmaf(w4.w, v.w, h[i]);
        }
      }
    }
#pragma unroll
    for (int i = 0; i < 4; ++i) {
      float y = fmaf(sc, h[i], sh);
      y = y >= 0.f ? y : 0.2f * y;
      mx = fmaxf(mx, y);
    }
  }
  redm[g][o] = mx;
  __syncthreads();
  if (t < 64) {
    float m = fmaxf(fmaxf(redm[0][o], redm[1][o]), fmaxf(redm[2][o], redm[3][o]));
    out[(size_t)b * OUTC + o0 + o] = m;
  }
}

extern "C" void kernel_launch(void* const* d_in, const int* in_sizes, int n_in,
                              void* d_out, int out_size, void* d_ws, size_t ws_size,
                              hipStream_t stream) {
  (void)in_sizes; (void)n_in; (void)out_size;
  const float* x  = (const float*)d_in[0];
  const float* W1 = (const float*)d_in[1];
  const float* g1 = (const float*)d_in[2];
  const float* b1 = (const float*)d_in[3];
  const float* W2 = (const float*)d_in[4];
  const float* g2 = (const float*)d_in[5];
  const float* b2 = (const float*)d_in[6];
  const float* W3 = (const float*)d_in[7];
  const float* g3 = (const float*)d_in[8];
  const float* b3 = (const float*)d_in[9];
  const float* Wf = (const float*)d_in[10];
  const float* gf = (const float*)d_in[11];
  const float* bf = (const float*)d_in[12];
  float* out = (float*)d_out;

  char* wsb = (char*)d_ws;
  float* F1f    = (float*)(wsb + 0);           // 8 MB
  float* F2f    = (float*)(wsb + 8388608);     // 8 MB
  float* F3f    = (float*)(wsb + 16777216);    // 8 MB
  float* xxf    = (float*)(wsb + 25165824);    // 128 KB
  int* idx      = (int*)(wsb + 25296896);      // 2.62 MB
  double* sumsd = (double*)(wsb + 27918336);   // 128 doubles
  double* fsums = (double*)(wsb + 27920384);   // 2048 doubles
  float* fscsh  = (float*)(wsb + 27936768);    // 2048 floats
  float* mrs    = (float*)(wsb + 27944960);    // 128 floats
  float* hbuf   = (float*)(wsb + 29360128);    // 167.8 MB (optional)
  const bool cache = ws_size >= (size_t)29360128 + (size_t)BB * NN * KNN * 64 * 4;

  const float* Fin[3] = {x, F1f, F2f};
  float* Fout[3] = {F1f, F2f, F3f};
  const float* Ws[3] = {W1, W2, W3};
  const float* gs[3] = {g1, g2, g3};
  const float* bs[3] = {b1, b2, b3};

  for (int L = 0; L < 3; ++L) {
    xx32_kernel<<<dim3(BB * NN / 256), 256, 0, stream>>>(Fin[L], xxf);
    knn_fast<<<dim3(NN / 64, BB), 256, 0, stream>>>(Fin[L], xxf, idx);
    hipMemsetAsync(sumsd, 0, 128 * sizeof(double), stream);
    if (cache)
      stats_k<1><<<dim3(NN / 64, BB), 256, 0, stream>>>(Fin[L], Ws[L], idx, sumsd, hbuf);
    else
      stats_k<0><<<dim3(NN / 64, BB), 256, 0, stream>>>(Fin[L], Ws[L], idx, sumsd, nullptr);
    finalize_np<<<1, 64, 0, stream>>>(sumsd, 1.0 / (double)(BB * NN * KNN), mrs);
    if (cache)
      apply_cached<<<dim3(BB * NN / 4), 256, 0, stream>>>(hbuf, mrs, gs[L], bs[L], Fout[L]);
    else
      apply_rec<<<dim3(NN / 64, BB), 256, 0, stream>>>(Fin[L], Ws[L], idx, mrs,
                                                       gs[L], bs[L], Fout[L]);
  }
  hipMemsetAsync(fsums, 0, 2048 * sizeof(double), stream);
  fstats32<<<dim3(OUTC / 64, BB), 256, 0, stream>>>(F1f, F2f, F3f, Wf, fsums);
  finalize_f<<<4, 256, 0, stream>>>(fsums, gf, bf, 1.0 / (double)(BB * NN), fscsh);
  fapply32<<<dim3(OUTC / 64, BB), 256, 0, stream>>>(F1f, F2f, F3f, Wf, fscsh, out);
}

// Round 11
// 3085.371 us; speedup vs baseline: 7.9548x; 1.2077x over previous
//
#include <hip/hip_runtime.h>

#define BB 16
#define NN 2048
#define CC 64
#define KNN 20
#define OUTC 1024

// ====== xx: numpy pairwise_sum(n=64, 8-acc path) over RN(f^2) ======
__global__ __launch_bounds__(256) void xx32_kernel(const float* __restrict__ F,
                                                   float* __restrict__ xxf) {
  int p = blockIdx.x * 256 + threadIdx.x;
  const float* f = F + (size_t)p * CC;
  float t[64];
#pragma unroll
  for (int c = 0; c < 64; ++c) t[c] = f[c] * f[c];
  float r[8];
#pragma unroll
  for (int j = 0; j < 8; ++j) r[j] = t[j];
#pragma unroll
  for (int i = 8; i < 64; i += 8)
#pragma unroll
    for (int j = 0; j < 8; ++j) r[j] += t[i + j];
  float res = ((r[0] + r[1]) + (r[2] + r[3])) + ((r[4] + r[5]) + (r[6] + r[7]));
  xxf[p] = res;
}

// ====== packed top-k key: monotone f32 score (hi) | inverted index (lo) ======
__device__ __forceinline__ unsigned long long packkey(float s, int m) {
  unsigned int u = __float_as_uint(s);
  u ^= (u >> 31) ? 0xFFFFFFFFu : 0x80000000u;
  return ((unsigned long long)u << 32) | (unsigned int)(NN - 1 - m);
}

#define INSERT_KEY(key)                                   \
  if ((key) > kv[KNN - 1]) {                              \
    _Pragma("unroll")                                     \
    for (int jj = KNN - 1; jj >= 1; --jj) {               \
      if ((key) > kv[jj - 1]) kv[jj] = kv[jj - 1];        \
      else if ((key) > kv[jj]) kv[jj] = (key);            \
    }                                                     \
    if ((key) > kv[0]) kv[0] = (key);                     \
  }

// ====== kNN: tiled gram (BLAS seq-ascending f32 chain per pair) + insertion top-k ======
__global__ __launch_bounds__(256) void knn_fast(const float* __restrict__ F,
                                                const float* __restrict__ xxf,
                                                int* __restrict__ idx) {
  __shared__ __align__(16) char smem[52736];
  float* SQc = (float*)smem;                  // [64 c][68]
  float* SPc = (float*)(smem + 17408);
  float* SS  = (float*)(smem + 34816);        // [64 row][68]
  float* xq  = (float*)(smem + 52224);
  float* xp  = (float*)(smem + 52480);

  int b = blockIdx.y, n0 = blockIdx.x * 64, t = threadIdx.x;
  const float* fb = F + (size_t)b * NN * CC;

#pragma unroll
  for (int j = 0; j < 4; ++j) {
    int v = t + 256 * j;
    int row = v >> 4, c4 = (v & 15) * 4;
    float4 val = *(const float4*)(fb + (size_t)(n0 + row) * CC + c4);
    SQc[(c4 + 0) * 68 + row] = val.x;
    SQc[(c4 + 1) * 68 + row] = val.y;
    SQc[(c4 + 2) * 68 + row] = val.z;
    SQc[(c4 + 3) * 68 + row] = val.w;
  }
  if (t < 64) xq[t] = xxf[b * NN + n0 + t];

  unsigned long long kv[KNN];
#pragma unroll
  for (int k = 0; k < KNN; ++k) kv[k] = 0ull;

  int tx = t & 15, ty = t >> 4;
  int r = t & 63, qq = t >> 6;

  for (int m0 = 0; m0 < NN; m0 += 64) {
    __syncthreads();
#pragma unroll
    for (int j = 0; j < 4; ++j) {
      int v = t + 256 * j;
      int row = v >> 4, c4 = (v & 15) * 4;
      float4 val = *(const float4*)(fb + (size_t)(m0 + row) * CC + c4);
      SPc[(c4 + 0) * 68 + row] = val.x;
      SPc[(c4 + 1) * 68 + row] = val.y;
      SPc[(c4 + 2) * 68 + row] = val.z;
      SPc[(c4 + 3) * 68 + row] = val.w;
    }
    if (t < 64) xp[t] = xxf[b * NN + m0 + t];
    __syncthreads();

    float acc[4][4] = {};
#pragma unroll 8
    for (int c = 0; c < 64; ++c) {
      float4 av = *(const float4*)&SQc[c * 68 + ty * 4];
      float4 bv = *(const float4*)&SPc[c * 68 + tx * 4];
      float a[4] = {av.x, av.y, av.z, av.w};
      float bb4[4] = {bv.x, bv.y, bv.z, bv.w};
#pragma unroll
      for (int i = 0; i < 4; ++i)
#pragma unroll
        for (int j = 0; j < 4; ++j) acc[i][j] = fmaf(a[i], bb4[j], acc[i][j]);
    }
#pragma unroll
    for (int i = 0; i < 4; ++i) {
      float xn = xq[ty * 4 + i];
      float4 sv;
      sv.x = (2.0f * acc[i][0] - xn) - xp[tx * 4 + 0];
      sv.y = (2.0f * acc[i][1] - xn) - xp[tx * 4 + 1];
      sv.z = (2.0f * acc[i][2] - xn) - xp[tx * 4 + 2];
      sv.w = (2.0f * acc[i][3] - xn) - xp[tx * 4 + 3];
      *(float4*)&SS[(ty * 4 + i) * 68 + tx * 4] = sv;
    }
    __syncthreads();

#pragma unroll
    for (int j4 = 0; j4 < 4; ++j4) {
      float4 sv = *(const float4*)&SS[r * 68 + qq * 16 + j4 * 4];
      int mb = m0 + qq * 16 + j4 * 4;
      unsigned long long k0 = packkey(sv.x, mb + 0);
      INSERT_KEY(k0)
      unsigned long long k1 = packkey(sv.y, mb + 1);
      INSERT_KEY(k1)
      unsigned long long k2 = packkey(sv.z, mb + 2);
      INSERT_KEY(k2)
      unsigned long long k3 = packkey(sv.w, mb + 3);
      INSERT_KEY(k3)
    }
  }

  __syncthreads();
  unsigned long long* keys = (unsigned long long*)smem;
#pragma unroll
  for (int k = 0; k < KNN; ++k) keys[t * KNN + k] = kv[k];
  __syncthreads();
  if (t < 64) {
    for (int q2 = 1; q2 < 4; ++q2) {
      int base = (q2 * 64 + t) * KNN;
#pragma unroll 1
      for (int k = 0; k < KNN; ++k) {
        unsigned long long key = keys[base + k];
        if (key <= kv[KNN - 1]) break;
        INSERT_KEY(key)
      }
    }
    int* dst = idx + (size_t)(b * NN + n0 + t) * KNN;
#pragma unroll
    for (int k = 0; k < KNN; ++k)
      dst[k] = (NN - 1) - (int)(unsigned int)(kv[k] & 0xFFFFFFFFull);
  }
}

// ====== EdgeConv stats: register-cached w, optional h cache ======
template <int CACHE>
__global__ __launch_bounds__(256) void stats_k(const float* __restrict__ F,
                                               const float* __restrict__ W,
                                               const int* __restrict__ idx,
                                               double* __restrict__ sums,
                                               float* __restrict__ hout) {
  __shared__ float Fn[64 * 64];
  __shared__ double rs[256], rss[256];
  int b = blockIdx.y, n0 = blockIdx.x * 64, t = threadIdx.x;
  int o = t & 63, g4 = t >> 6;
#pragma unroll
  for (int j = 0; j < 4; ++j) {
    int v = t + 256 * j;
    int row = v >> 4, c4 = (v & 15) * 4;
    *(float4*)&Fn[row * 64 + c4] =
        *(const float4*)(F + ((size_t)(b * NN + n0 + row)) * CC + c4);
  }
  float4 w0[16], w1[16];
  const float* wp = W + o * 128;
#pragma unroll
  for (int c4 = 0; c4 < 16; ++c4) {
    w0[c4] = *(const float4*)(wp + c4 * 4);
    w1[c4] = *(const float4*)(wp + 64 + c4 * 4);
  }
  __syncthreads();
  double s = 0.0, ss = 0.0;
  for (int i = 0; i < 16; ++i) {
    int n = n0 + g4 * 16 + i;
    float4 fn[16];
#pragma unroll
    for (int c4 = 0; c4 < 16; ++c4) fn[c4] = *(float4*)&Fn[(g4 * 16 + i) * 64 + c4 * 4];
    const int* ip = idx + ((size_t)(b * NN + n)) * KNN;
#pragma unroll 1
    for (int k = 0; k < KNN; k += 2) {
      const float* fp0 = F + ((size_t)(b * NN + ip[k])) * CC;
      const float* fp1 = F + ((size_t)(b * NN + ip[k + 1])) * CC;
      float a0 = 0.f, a1 = 0.f;
#pragma unroll
      for (int c4 = 0; c4 < 16; ++c4) {
        float4 f0 = *(const float4*)(fp0 + c4 * 4);
        float4 f1 = *(const float4*)(fp1 + c4 * 4);
        float4 fv = fn[c4], wv = w0[c4];
        a0 = fmaf(wv.x, f0.x - fv.x, a0);
        a0 = fmaf(wv.y, f0.y - fv.y, a0);
        a0 = fmaf(wv.z, f0.z - fv.z, a0);
        a0 = fmaf(wv.w, f0.w - fv.w, a0);
        a1 = fmaf(wv.x, f1.x - fv.x, a1);
        a1 = fmaf(wv.y, f1.y - fv.y, a1);
        a1 = fmaf(wv.z, f1.z - fv.z, a1);
        a1 = fmaf(wv.w, f1.w - fv.w, a1);
      }
#pragma unroll
      for (int c4 = 0; c4 < 16; ++c4) {
        float4 fv = fn[c4], wv = w1[c4];
        a0 = fmaf(wv.x, fv.x, a0);
        a0 = fmaf(wv.y, fv.y, a0);
        a0 = fmaf(wv.z, fv.z, a0);
        a0 = fmaf(wv.w, fv.w, a0);
        a1 = fmaf(wv.x, fv.x, a1);
        a1 = fmaf(wv.y, fv.y, a1);
        a1 = fmaf(wv.z, fv.z, a1);
        a1 = fmaf(wv.w, fv.w, a1);
      }
      s += (double)a0 + (double)a1;
      ss += (double)a0 * (double)a0 + (double)a1 * (double)a1;
      if (CACHE) {
        float* hp = hout + (((size_t)(b * NN + n)) * KNN + k) * 64 + o;
        hp[0] = a0;
        hp[64] = a1;
      }
    }
  }
  rs[t] = s; rss[t] = ss;
  __syncthreads();
  if (t < 64) {
    double a = rs[t] + rs[t + 64] + rs[t + 128] + rs[t + 192];
    double q = rss[t] + rss[t + 64] + rss[t + 128] + rss[t + 192];
    atomicAdd(&sums[o], a);
    atomicAdd(&sums[64 + o], q);
  }
}

// ====== BN finalize for edge layers: f32 mean + f32 rs ======
__global__ void finalize_np(const double* __restrict__ sums, double cntinv,
                            float* __restrict__ mrs) {
  int c = threadIdx.x;  // 64
  double mean = sums[c] * cntinv;
  double var = sums[64 + c] * cntinv - mean * mean;
  mrs[c] = (float)mean;
  mrs[64 + c] = 1.0f / sqrtf((float)var + 1e-5f);
}

// ====== apply (cached h): streaming normalize + max over k ======
__global__ __launch_bounds__(256) void apply_cached(const float* __restrict__ hin,
                                                    const float* __restrict__ mrs,
                                                    const float* __restrict__ gv,
                                                    const float* __restrict__ bvv,
                                                    float* __restrict__ Fo) {
  int t = threadIdx.x;
  int o = t & 63, ng = t >> 6;
  size_t n = (size_t)blockIdx.x * 4 + ng;
  const float* hp = hin + n * KNN * 64 + o;
  float m32 = mrs[o], rs32 = mrs[64 + o];
  float gg = gv[o], bb = bvv[o];
  float mx = -3.0e38f;
#pragma unroll
  for (int k = 0; k < KNN; ++k) {
    float h = hp[k * 64];
    float d = h - m32;
    d = d * rs32;
    d = d * gg;
    float y = d + bb;
    y = y >= 0.f ? y : 0.2f * y;
    mx = fmaxf(mx, y);
  }
  Fo[n * 64 + o] = mx;
}

// ====== apply (recompute fallback) ======
__global__ __launch_bounds__(256) void apply_rec(const float* __restrict__ F,
                                                 const float* __restrict__ W,
                                                 const int* __restrict__ idx,
                                                 const float* __restrict__ mrs,
                                                 const float* __restrict__ gv,
                                                 const float* __restrict__ bvv,
                                                 float* __restrict__ Fo) {
  __shared__ float Fn[64 * 64];
  int b = blockIdx.y, n0 = blockIdx.x * 64, t = threadIdx.x;
  int o = t & 63, g4 = t >> 6;
#pragma unroll
  for (int j = 0; j < 4; ++j) {
    int v = t + 256 * j;
    int row = v >> 4, c4 = (v & 15) * 4;
    *(float4*)&Fn[row * 64 + c4] =
        *(const float4*)(F + ((size_t)(b * NN + n0 + row)) * CC + c4);
  }
  float4 w0[16], w1[16];
  const float* wp = W + o * 128;
#pragma unroll
  for (int c4 = 0; c4 < 16; ++c4) {
    w0[c4] = *(const float4*)(wp + c4 * 4);
    w1[c4] = *(const float4*)(wp + 64 + c4 * 4);
  }
  __syncthreads();
  float m32 = mrs[o], rs32 = mrs[64 + o];
  float gg = gv[o], bb = bvv[o];
  for (int i = 0; i < 16; ++i) {
    int n = n0 + g4 * 16 + i;
    float4 fn[16];
#pragma unroll
    for (int c4 = 0; c4 < 16; ++c4) fn[c4] = *(float4*)&Fn[(g4 * 16 + i) * 64 + c4 * 4];
    const int* ip = idx + ((size_t)(b * NN + n)) * KNN;
    float mx = -3.0e38f;
#pragma unroll 1
    for (int k = 0; k < KNN; k += 2) {
      const float* fp0 = F + ((size_t)(b * NN + ip[k])) * CC;
      const float* fp1 = F + ((size_t)(b * NN + ip[k + 1])) * CC;
      float a0 = 0.f, a1 = 0.f;
#pragma unroll
      for (int c4 = 0; c4 < 16; ++c4) {
        float4 f0 = *(const float4*)(fp0 + c4 * 4);
        float4 f1 = *(const float4*)(fp1 + c4 * 4);
        float4 fv = fn[c4], wv = w0[c4];
        a0 = fmaf(wv.x, f0.x - fv.x, a0);
        a0 = fmaf(wv.y, f0.y - fv.y, a0);
        a0 = fmaf(wv.z, f0.z - fv.z, a0);
        a0 = fmaf(wv.w, f0.w - fv.w, a0);
        a1 = fmaf(wv.x, f1.x - fv.x, a1);
        a1 = fmaf(wv.y, f1.y - fv.y, a1);
        a1 = fmaf(wv.z, f1.z - fv.z, a1);
        a1 = fmaf(wv.w, f1.w - fv.w, a1);
      }
#pragma unroll
      for (int c4 = 0; c4 < 16; ++c4) {
        float4 fv = fn[c4], wv = w1[c4];
        a0 = fmaf(wv.x, fv.x, a0);
        a0 = fmaf(wv.y, fv.y, a0);
        a0 = fmaf(wv.z, fv.z, a0);
        a0 = fmaf(wv.w, fv.w, a0);
        a1 = fmaf(wv.x, fv.x, a1);
        a1 = fmaf(wv.y, fv.y, a1);
        a1 = fmaf(wv.z, fv.z, a1);
        a1 = fmaf(wv.w, fv.w, a1);
      }
      float d0 = a0 - m32; d0 = d0 * rs32; d0 = d0 * gg;
      float y0 = d0 + bb;
      y0 = y0 >= 0.f ? y0 : 0.2f * y0;
      float d1 = a1 - m32; d1 = d1 * rs32; d1 = d1 * gg;
      float y1 = d1 + bb;
      y1 = y1 >= 0.f ? y1 : 0.2f * y1;
      mx = fmaxf(mx, fmaxf(y0, y1));
    }
    Fo[((size_t)(b * NN + n)) * CC + o] = mx;
  }
}

// ====== final stats, n-split, optional h cache ([b][n][OUTC]) ======
template <int CACHE>
__global__ __launch_bounds__(256) void fstats_split(const float* __restrict__ F1,
                                                    const float* __restrict__ F2,
                                                    const float* __restrict__ F3,
                                                    const float* __restrict__ Wf,
                                                    double* __restrict__ sums,
                                                    float* __restrict__ hout) {
  __shared__ float Wl[64 * 193];
  __shared__ double rs[256], rss[256];
  int b = blockIdx.y, o0 = blockIdx.x * 64, t = threadIdx.x;
  int nbase = blockIdx.z * (NN / 8);
  for (int j = 0; j < 48; ++j) {
    int v = t + 256 * j;
    int oo = v / 192, c = v - oo * 192;
    Wl[oo * 193 + c] = Wf[(size_t)(o0 + oo) * 192 + c];
  }
  __syncthreads();
  int o = t & 63, g = t >> 6;
  const float* fs[3] = {F1, F2, F3};
  double s = 0.0, ss = 0.0;
  for (int n0 = nbase; n0 < nbase + NN / 8; n0 += 16) {
    int n = n0 + g * 4;
    float h[4] = {0.f, 0.f, 0.f, 0.f};
#pragma unroll
    for (int part = 0; part < 3; ++part) {
      const float* src = fs[part] + ((size_t)(b * NN + n)) * CC;
      const float* wp = &Wl[o * 193 + part * 64];
#pragma unroll 4
      for (int c4 = 0; c4 < 16; ++c4) {
        float4 w4 = {wp[c4 * 4], wp[c4 * 4 + 1], wp[c4 * 4 + 2], wp[c4 * 4 + 3]};
#pragma unroll
        for (int i = 0; i < 4; ++i) {
          float4 v = *(const float4*)(src + (size_t)i * CC + c4 * 4);
          h[i] = fmaf(w4.x, v.x, h[i]);
          h[i] = fmaf(w4.y, v.y, h[i]);
          h[i] = fmaf(w4.z, v.z, h[i]);
          h[i] = fmaf(w4.w, v.w, h[i]);
        }
      }
    }
#pragma unroll
    for (int i = 0; i < 4; ++i) {
      s += (double)h[i];
      ss += (double)h[i] * (double)h[i];
      if (CACHE) hout[((size_t)(b * NN + n + i)) * OUTC + o0 + o] = h[i];
    }
  }
  rs[t] = s; rss[t] = ss;
  __syncthreads();
  if (t < 64) {
    double a = rs[t] + rs[t + 64] + rs[t + 128] + rs[t + 192];
    double q = rss[t] + rss[t + 64] + rss[t + 128] + rss[t + 192];
    atomicAdd(&sums[o0 + o], a);
    atomicAdd(&sums[1024 + o0 + o], q);
  }
}

// ====== BN finalize (final layer): f64 math -> f32 sc/sh ======
__global__ void finalize_f(const double* __restrict__ sums,
                           const float* __restrict__ g,
                           const float* __restrict__ bb, double cntinv,
                           float* __restrict__ scsh) {
  int c = blockIdx.x * 256 + threadIdx.x;  // 1024
  double mean = sums[c] * cntinv;
  double var = sums[1024 + c] * cntinv - mean * mean;
  double sc = (double)g[c] / sqrt(var + 1e-5);
  scsh[c] = (float)sc;
  scsh[1024 + c] = (float)((double)bb[c] - mean * sc);
}

// ====== final apply from h cache: normalize + partial max over n chunk ======
__global__ __launch_bounds__(256) void fapply_stream(const float* __restrict__ hin,
                                                     const float* __restrict__ scsh,
                                                     float* __restrict__ pmax) {
  int b = blockIdx.y, t = threadIdx.x;
  int o = blockIdx.x * 256 + t;
  int nbase = blockIdx.z * (NN / 8);
  float sc = scsh[o], sh = scsh[1024 + o];
  float mx = -3.0e38f;
  const float* hp = hin + ((size_t)(b * NN + nbase)) * OUTC + o;
#pragma unroll 4
  for (int n = 0; n < NN / 8; ++n) {
    float y = fmaf(sc, hp[(size_t)n * OUTC], sh);
    y = y >= 0.f ? y : 0.2f * y;
    mx = fmaxf(mx, y);
  }
  pmax[((size_t)blockIdx.z * BB + b) * OUTC + o] = mx;
}

__global__ __launch_bounds__(256) void freduce(const float* __restrict__ pmax,
                                               float* __restrict__ out) {
  int v = blockIdx.x * 256 + threadIdx.x;  // b*OUTC+o
  float mx = -3.0e38f;
#pragma unroll
  for (int ch = 0; ch < 8; ++ch) mx = fmaxf(mx, pmax[(size_t)ch * BB * OUTC + v]);
  out[v] = mx;
}

// ====== fallback final kernels (no cache) ======
__global__ __launch_bounds__(256) void fapply32(const float* __restrict__ F1,
                                                const float* __restrict__ F2,
                                                const float* __restrict__ F3,
                                                const float* __restrict__ Wf,
                                                const float* __restrict__ scsh,
                                                float* __restrict__ out) {
  __shared__ float Wl[64 * 193];
  __shared__ float redm[4][64];
  int b = blockIdx.y, o0 = blockIdx.x * 64, t = threadIdx.x;
  for (int j = 0; j < 48; ++j) {
    int v = t + 256 * j;
    int oo = v / 192, c = v - oo * 192;
    Wl[oo * 193 + c] = Wf[(size_t)(o0 + oo) * 192 + c];
  }
  __syncthreads();
  int o = t & 63, g = t >> 6;
  float sc = scsh[o0 + o], sh = scsh[1024 + o0 + o];
  const float* fs[3] = {F1, F2, F3};
  float mx = -3.0e38f;
  for (int n0 = 0; n0 < NN; n0 += 16) {
    int n = n0 + g * 4;
    float h[4] = {0.f, 0.f, 0.f, 0.f};
#pragma unroll
    for (int part = 0; part < 3; ++part) {
      const float* src = fs[part] + ((size_t)(b * NN + n)) * CC;
      const float* wp = &Wl[o * 193 + part * 64];
#pragma unroll 4
      for (int c4 = 0; c4 < 16; ++c4) {
        float4 w4 = {wp[c4 * 4], wp[c4 * 4 + 1], wp[c4 * 4 + 2], wp[c4 * 4 + 3]};
#pragma unroll
        for (int i = 0; i < 4; ++i) {
          float4 v = *(const float4*)(src + (size_t)i * CC + c4 * 4);
          h[i] = fmaf(w4.x, v.x, h[i]);
          h[i] = fmaf(w4.y, v.y, h[i]);
          h[i] = fmaf(w4.z, v.z, h[i]);
          h[i] = fmaf(w4.w, v.w, h[i]);
        }
      }
    }
#pragma unroll
    for (int i = 0; i < 4; ++i) {
      float y = fmaf(sc, h[i], sh);
      y = y >= 0.f ? y : 0.2f * y;
      mx = fmaxf(mx, y);
    }
  }
  redm[g][o] = mx;
  __syncthreads();
  if (t < 64) {
    float m = fmaxf(fmaxf(redm[0][o], redm[1][o]), fmaxf(redm[2][o], redm[3][o]));
    out[(size_t)b * OUTC + o0 + o] = m;
  }
}

extern "C" void kernel_launch(void* const* d_in, const int* in_sizes, int n_in,
                              void* d_out, int out_size, void* d_ws, size_t ws_size,
                              hipStream_t stream) {
  (void)in_sizes; (void)n_in; (void)out_size;
  const float* x  = (const float*)d_in[0];
  const float* W1 = (const float*)d_in[1];
  const float* g1 = (const float*)d_in[2];
  const float* b1 = (const float*)d_in[3];
  const float* W2 = (const float*)d_in[4];
  const float* g2 = (const float*)d_in[5];
  const float* b2 = (const float*)d_in[6];
  const float* W3 = (const float*)d_in[7];
  const float* g3 = (const float*)d_in[8];
  const float* b3 = (const float*)d_in[9];
  const float* Wf = (const float*)d_in[10];
  const float* gf = (const float*)d_in[11];
  const float* bf = (const float*)d_in[12];
  float* out = (float*)d_out;

  char* wsb = (char*)d_ws;
  float* F1f    = (float*)(wsb + 0);           // 8 MB
  float* F2f    = (float*)(wsb + 8388608);     // 8 MB
  float* F3f    = (float*)(wsb + 16777216);    // 8 MB
  float* xxf    = (float*)(wsb + 25165824);    // 128 KB
  int* idx      = (int*)(wsb + 25296896);      // 2.62 MB
  double* sumsd = (double*)(wsb + 27918336);   // 128 doubles
  double* fsums = (double*)(wsb + 27920384);   // 2048 doubles
  float* fscsh  = (float*)(wsb + 27936768);    // 2048 floats
  float* mrs    = (float*)(wsb + 27944960);    // 128 floats
  float* pmax   = (float*)(wsb + 27945984);    // 512 KB (8*16*1024 floats)
  float* hbuf   = (float*)(wsb + 29360128);    // 167.8 MB (optional)
  const bool cache = ws_size >= (size_t)29360128 + (size_t)BB * NN * KNN * 64 * 4;

  const float* Fin[3] = {x, F1f, F2f};
  float* Fout[3] = {F1f, F2f, F3f};
  const float* Ws[3] = {W1, W2, W3};
  const float* gs[3] = {g1, g2, g3};
  const float* bs[3] = {b1, b2, b3};

  for (int L = 0; L < 3; ++L) {
    xx32_kernel<<<dim3(BB * NN / 256), 256, 0, stream>>>(Fin[L], xxf);
    knn_fast<<<dim3(NN / 64, BB), 256, 0, stream>>>(Fin[L], xxf, idx);
    hipMemsetAsync(sumsd, 0, 128 * sizeof(double), stream);
    if (cache)
      stats_k<1><<<dim3(NN / 64, BB), 256, 0, stream>>>(Fin[L], Ws[L], idx, sumsd, hbuf);
    else
      stats_k<0><<<dim3(NN / 64, BB), 256, 0, stream>>>(Fin[L], Ws[L], idx, sumsd, nullptr);
    finalize_np<<<1, 64, 0, stream>>>(sumsd, 1.0 / (double)(BB * NN * KNN), mrs);
    if (cache)
      apply_cached<<<dim3(BB * NN / 4), 256, 0, stream>>>(hbuf, mrs, gs[L], bs[L], Fout[L]);
    else
      apply_rec<<<dim3(NN / 64, BB), 256, 0, stream>>>(Fin[L], Ws[L], idx, mrs,
                                                       gs[L], bs[L], Fout[L]);
  }
  hipMemsetAsync(fsums, 0, 2048 * sizeof(double), stream);
  if (cache) {
    // hbuf free after layer-3 apply; final h = 134 MB <= 167.8 MB region
    fstats_split<1><<<dim3(OUTC / 64, BB, 8), 256, 0, stream>>>(F1f, F2f, F3f, Wf,
                                                                fsums, hbuf);
    finalize_f<<<4, 256, 0, stream>>>(fsums, gf, bf, 1.0 / (double)(BB * NN), fscsh);
    fapply_stream<<<dim3(OUTC / 256, BB, 8), 256, 0, stream>>>(hbuf, fscsh, pmax);
    freduce<<<dim3(BB * OUTC / 256), 256, 0, stream>>>(pmax, out);
  } else {
    fstats_split<0><<<dim3(OUTC / 64, BB, 8), 256, 0, stream>>>(F1f, F2f, F3f, Wf,
                                                                fsums, nullptr);
    finalize_f<<<4, 256, 0, stream>>>(fsums, gf, bf, 1.0 / (double)(BB * NN), fscsh);
    fapply32<<<dim3(OUTC / 64, BB), 256, 0, stream>>>(F1f, F2f, F3f, Wf, fscsh, out);
  }
}

// Round 12
// 2616.544 us; speedup vs baseline: 9.3802x; 1.1792x over previous
//
#include <hip/hip_runtime.h>

#define BB 16
#define NN 2048
#define CC 64
#define KNN 20
#define OUTC 1024

// ====== xx: numpy pairwise_sum(n=64, 8-acc path) over RN(f^2) ======
__global__ __launch_bounds__(256) void xx32_kernel(const float* __restrict__ F,
                                                   float* __restrict__ xxf) {
  int p = blockIdx.x * 256 + threadIdx.x;
  const float* f = F + (size_t)p * CC;
  float t[64];
#pragma unroll
  for (int c = 0; c < 64; ++c) t[c] = f[c] * f[c];
  float r[8];
#pragma unroll
  for (int j = 0; j < 8; ++j) r[j] = t[j];
#pragma unroll
  for (int i = 8; i < 64; i += 8)
#pragma unroll
    for (int j = 0; j < 8; ++j) r[j] += t[i + j];
  float res = ((r[0] + r[1]) + (r[2] + r[3])) + ((r[4] + r[5]) + (r[6] + r[7]));
  xxf[p] = res;
}

// ====== packed top-k key: monotone f32 score (hi) | inverted index (lo) ======
__device__ __forceinline__ unsigned long long packkey(float s, int m) {
  unsigned int u = __float_as_uint(s);
  u ^= (u >> 31) ? 0xFFFFFFFFu : 0x80000000u;
  return ((unsigned long long)u << 32) | (unsigned int)(NN - 1 - m);
}

#define INSERT_KEY(key)                                   \
  if ((key) > kv[KNN - 1]) {                              \
    _Pragma("unroll")                                     \
    for (int jj = KNN - 1; jj >= 1; --jj) {               \
      if ((key) > kv[jj - 1]) kv[jj] = kv[jj - 1];        \
      else if ((key) > kv[jj]) kv[jj] = (key);            \
    }                                                     \
    if ((key) > kv[0]) kv[0] = (key);                     \
  }

// ====== kNN: tiled gram (BLAS seq-ascending f32 chain per pair) + insertion top-k ======
__global__ __launch_bounds__(256) void knn_fast(const float* __restrict__ F,
                                                const float* __restrict__ xxf,
                                                int* __restrict__ idx) {
  __shared__ __align__(16) char smem[52736];
  float* SQc = (float*)smem;                  // [64 c][68]
  float* SPc = (float*)(smem + 17408);
  float* SS  = (float*)(smem + 34816);        // [64 row][68]
  float* xq  = (float*)(smem + 52224);
  float* xp  = (float*)(smem + 52480);

  int b = blockIdx.y, n0 = blockIdx.x * 64, t = threadIdx.x;
  const float* fb = F + (size_t)b * NN * CC;

#pragma unroll
  for (int j = 0; j < 4; ++j) {
    int v = t + 256 * j;
    int row = v >> 4, c4 = (v & 15) * 4;
    float4 val = *(const float4*)(fb + (size_t)(n0 + row) * CC + c4);
    SQc[(c4 + 0) * 68 + row] = val.x;
    SQc[(c4 + 1) * 68 + row] = val.y;
    SQc[(c4 + 2) * 68 + row] = val.z;
    SQc[(c4 + 3) * 68 + row] = val.w;
  }
  if (t < 64) xq[t] = xxf[b * NN + n0 + t];

  unsigned long long kv[KNN];
#pragma unroll
  for (int k = 0; k < KNN; ++k) kv[k] = 0ull;

  int tx = t & 15, ty = t >> 4;
  int r = t & 63, qq = t >> 6;

  for (int m0 = 0; m0 < NN; m0 += 64) {
    __syncthreads();
#pragma unroll
    for (int j = 0; j < 4; ++j) {
      int v = t + 256 * j;
      int row = v >> 4, c4 = (v & 15) * 4;
      float4 val = *(const float4*)(fb + (size_t)(m0 + row) * CC + c4);
      SPc[(c4 + 0) * 68 + row] = val.x;
      SPc[(c4 + 1) * 68 + row] = val.y;
      SPc[(c4 + 2) * 68 + row] = val.z;
      SPc[(c4 + 3) * 68 + row] = val.w;
    }
    if (t < 64) xp[t] = xxf[b * NN + m0 + t];
    __syncthreads();

    float acc[4][4] = {};
#pragma unroll 8
    for (int c = 0; c < 64; ++c) {
      float4 av = *(const float4*)&SQc[c * 68 + ty * 4];
      float4 bv = *(const float4*)&SPc[c * 68 + tx * 4];
      float a[4] = {av.x, av.y, av.z, av.w};
      float bb4[4] = {bv.x, bv.y, bv.z, bv.w};
#pragma unroll
      for (int i = 0; i < 4; ++i)
#pragma unroll
        for (int j = 0; j < 4; ++j) acc[i][j] = fmaf(a[i], bb4[j], acc[i][j]);
    }
#pragma unroll
    for (int i = 0; i < 4; ++i) {
      float xn = xq[ty * 4 + i];
      float4 sv;
      sv.x = (2.0f * acc[i][0] - xn) - xp[tx * 4 + 0];
      sv.y = (2.0f * acc[i][1] - xn) - xp[tx * 4 + 1];
      sv.z = (2.0f * acc[i][2] - xn) - xp[tx * 4 + 2];
      sv.w = (2.0f * acc[i][3] - xn) - xp[tx * 4 + 3];
      *(float4*)&SS[(ty * 4 + i) * 68 + tx * 4] = sv;
    }
    __syncthreads();

#pragma unroll
    for (int j4 = 0; j4 < 4; ++j4) {
      float4 sv = *(const float4*)&SS[r * 68 + qq * 16 + j4 * 4];
      int mb = m0 + qq * 16 + j4 * 4;
      unsigned long long k0 = packkey(sv.x, mb + 0);
      INSERT_KEY(k0)
      unsigned long long k1 = packkey(sv.y, mb + 1);
      INSERT_KEY(k1)
      unsigned long long k2 = packkey(sv.z, mb + 2);
      INSERT_KEY(k2)
      unsigned long long k3 = packkey(sv.w, mb + 3);
      INSERT_KEY(k3)
    }
  }

  __syncthreads();
  unsigned long long* keys = (unsigned long long*)smem;
#pragma unroll
  for (int k = 0; k < KNN; ++k) keys[t * KNN + k] = kv[k];
  __syncthreads();
  if (t < 64) {
    for (int q2 = 1; q2 < 4; ++q2) {
      int base = (q2 * 64 + t) * KNN;
#pragma unroll 1
      for (int k = 0; k < KNN; ++k) {
        unsigned long long key = keys[base + k];
        if (key <= kv[KNN - 1]) break;
        INSERT_KEY(key)
      }
    }
    int* dst = idx + (size_t)(b * NN + n0 + t) * KNN;
#pragma unroll
    for (int k = 0; k < KNN; ++k)
      dst[k] = (NN - 1) - (int)(unsigned int)(kv[k] & 0xFFFFFFFFull);
  }
}

// ====== EdgeConv stats: register-cached w, optional h cache ======
template <int CACHE>
__global__ __launch_bounds__(256) void stats_k(const float* __restrict__ F,
                                               const float* __restrict__ W,
                                               const int* __restrict__ idx,
                                               double* __restrict__ sums,
                                               float* __restrict__ hout) {
  __shared__ float Fn[64 * 64];
  __shared__ double rs[256], rss[256];
  int b = blockIdx.y, n0 = blockIdx.x * 64, t = threadIdx.x;
  int o = t & 63, g4 = t >> 6;
#pragma unroll
  for (int j = 0; j < 4; ++j) {
    int v = t + 256 * j;
    int row = v >> 4, c4 = (v & 15) * 4;
    *(float4*)&Fn[row * 64 + c4] =
        *(const float4*)(F + ((size_t)(b * NN + n0 + row)) * CC + c4);
  }
  float4 w0[16], w1[16];
  const float* wp = W + o * 128;
#pragma unroll
  for (int c4 = 0; c4 < 16; ++c4) {
    w0[c4] = *(const float4*)(wp + c4 * 4);
    w1[c4] = *(const float4*)(wp + 64 + c4 * 4);
  }
  __syncthreads();
  double s = 0.0, ss = 0.0;
  for (int i = 0; i < 16; ++i) {
    int n = n0 + g4 * 16 + i;
    float4 fn[16];
#pragma unroll
    for (int c4 = 0; c4 < 16; ++c4) fn[c4] = *(float4*)&Fn[(g4 * 16 + i) * 64 + c4 * 4];
    const int* ip = idx + ((size_t)(b * NN + n)) * KNN;
#pragma unroll 1
    for (int k = 0; k < KNN; k += 2) {
      const float* fp0 = F + ((size_t)(b * NN + ip[k])) * CC;
      const float* fp1 = F + ((size_t)(b * NN + ip[k + 1])) * CC;
      float a0 = 0.f, a1 = 0.f;
#pragma unroll
      for (int c4 = 0; c4 < 16; ++c4) {
        float4 f0 = *(const float4*)(fp0 + c4 * 4);
        float4 f1 = *(const float4*)(fp1 + c4 * 4);
        float4 fv = fn[c4], wv = w0[c4];
        a0 = fmaf(wv.x, f0.x - fv.x, a0);
        a0 = fmaf(wv.y, f0.y - fv.y, a0);
        a0 = fmaf(wv.z, f0.z - fv.z, a0);
        a0 = fmaf(wv.w, f0.w - fv.w, a0);
        a1 = fmaf(wv.x, f1.x - fv.x, a1);
        a1 = fmaf(wv.y, f1.y - fv.y, a1);
        a1 = fmaf(wv.z, f1.z - fv.z, a1);
        a1 = fmaf(wv.w, f1.w - fv.w, a1);
      }
#pragma unroll
      for (int c4 = 0; c4 < 16; ++c4) {
        float4 fv = fn[c4], wv = w1[c4];
        a0 = fmaf(wv.x, fv.x, a0);
        a0 = fmaf(wv.y, fv.y, a0);
        a0 = fmaf(wv.z, fv.z, a0);
        a0 = fmaf(wv.w, fv.w, a0);
        a1 = fmaf(wv.x, fv.x, a1);
        a1 = fmaf(wv.y, fv.y, a1);
        a1 = fmaf(wv.z, fv.z, a1);
        a1 = fmaf(wv.w, fv.w, a1);
      }
      s += (double)a0 + (double)a1;
      ss += (double)a0 * (double)a0 + (double)a1 * (double)a1;
      if (CACHE) {
        float* hp = hout + (((size_t)(b * NN + n)) * KNN + k) * 64 + o;
        hp[0] = a0;
        hp[64] = a1;
      }
    }
  }
  rs[t] = s; rss[t] = ss;
  __syncthreads();
  if (t < 64) {
    double a = rs[t] + rs[t + 64] + rs[t + 128] + rs[t + 192];
    double q = rss[t] + rss[t + 64] + rss[t + 128] + rss[t + 192];
    atomicAdd(&sums[o], a);
    atomicAdd(&sums[64 + o], q);
  }
}

// ====== BN finalize for edge layers: f32 mean + f32 rs ======
__global__ void finalize_np(const double* __restrict__ sums, double cntinv,
                            float* __restrict__ mrs) {
  int c = threadIdx.x;  // 64
  double mean = sums[c] * cntinv;
  double var = sums[64 + c] * cntinv - mean * mean;
  mrs[c] = (float)mean;
  mrs[64 + c] = 1.0f / sqrtf((float)var + 1e-5f);
}

// ====== apply (cached h): streaming normalize + max over k ======
__global__ __launch_bounds__(256) void apply_cached(const float* __restrict__ hin,
                                                    const float* __restrict__ mrs,
                                                    const float* __restrict__ gv,
                                                    const float* __restrict__ bvv,
                                                    float* __restrict__ Fo) {
  int t = threadIdx.x;
  int o = t & 63, ng = t >> 6;
  size_t n = (size_t)blockIdx.x * 4 + ng;
  const float* hp = hin + n * KNN * 64 + o;
  float m32 = mrs[o], rs32 = mrs[64 + o];
  float gg = gv[o], bb = bvv[o];
  float mx = -3.0e38f;
#pragma unroll
  for (int k = 0; k < KNN; ++k) {
    float h = hp[k * 64];
    float d = h - m32;
    d = d * rs32;
    d = d * gg;
    float y = d + bb;
    y = y >= 0.f ? y : 0.2f * y;
    mx = fmaxf(mx, y);
  }
  Fo[n * 64 + o] = mx;
}

// ====== apply (recompute fallback) ======
__global__ __launch_bounds__(256) void apply_rec(const float* __restrict__ F,
                                                 const float* __restrict__ W,
                                                 const int* __restrict__ idx,
                                                 const float* __restrict__ mrs,
                                                 const float* __restrict__ gv,
                                                 const float* __restrict__ bvv,
                                                 float* __restrict__ Fo) {
  __shared__ float Fn[64 * 64];
  int b = blockIdx.y, n0 = blockIdx.x * 64, t = threadIdx.x;
  int o = t & 63, g4 = t >> 6;
#pragma unroll
  for (int j = 0; j < 4; ++j) {
    int v = t + 256 * j;
    int row = v >> 4, c4 = (v & 15) * 4;
    *(float4*)&Fn[row * 64 + c4] =
        *(const float4*)(F + ((size_t)(b * NN + n0 + row)) * CC + c4);
  }
  float4 w0[16], w1[16];
  const float* wp = W + o * 128;
#pragma unroll
  for (int c4 = 0; c4 < 16; ++c4) {
    w0[c4] = *(const float4*)(wp + c4 * 4);
    w1[c4] = *(const float4*)(wp + 64 + c4 * 4);
  }
  __syncthreads();
  float m32 = mrs[o], rs32 = mrs[64 + o];
  float gg = gv[o], bb = bvv[o];
  for (int i = 0; i < 16; ++i) {
    int n = n0 + g4 * 16 + i;
    float4 fn[16];
#pragma unroll
    for (int c4 = 0; c4 < 16; ++c4) fn[c4] = *(float4*)&Fn[(g4 * 16 + i) * 64 + c4 * 4];
    const int* ip = idx + ((size_t)(b * NN + n)) * KNN;
    float mx = -3.0e38f;
#pragma unroll 1
    for (int k = 0; k < KNN; k += 2) {
      const float* fp0 = F + ((size_t)(b * NN + ip[k])) * CC;
      const float* fp1 = F + ((size_t)(b * NN + ip[k + 1])) * CC;
      float a0 = 0.f, a1 = 0.f;
#pragma unroll
      for (int c4 = 0; c4 < 16; ++c4) {
        float4 f0 = *(const float4*)(fp0 + c4 * 4);
        float4 f1 = *(const float4*)(fp1 + c4 * 4);
        float4 fv = fn[c4], wv = w0[c4];
        a0 = fmaf(wv.x, f0.x - fv.x, a0);
        a0 = fmaf(wv.y, f0.y - fv.y, a0);
        a0 = fmaf(wv.z, f0.z - fv.z, a0);
        a0 = fmaf(wv.w, f0.w - fv.w, a0);
        a1 = fmaf(wv.x, f1.x - fv.x, a1);
        a1 = fmaf(wv.y, f1.y - fv.y, a1);
        a1 = fmaf(wv.z, f1.z - fv.z, a1);
        a1 = fmaf(wv.w, f1.w - fv.w, a1);
      }
#pragma unroll
      for (int c4 = 0; c4 < 16; ++c4) {
        float4 fv = fn[c4], wv = w1[c4];
        a0 = fmaf(wv.x, fv.x, a0);
        a0 = fmaf(wv.y, fv.y, a0);
        a0 = fmaf(wv.z, fv.z, a0);
        a0 = fmaf(wv.w, fv.w, a0);
        a1 = fmaf(wv.x, fv.x, a1);
        a1 = fmaf(wv.y, fv.y, a1);
        a1 = fmaf(wv.z, fv.z, a1);
        a1 = fmaf(wv.w, fv.w, a1);
      }
      float d0 = a0 - m32; d0 = d0 * rs32; d0 = d0 * gg;
      float y0 = d0 + bb;
      y0 = y0 >= 0.f ? y0 : 0.2f * y0;
      float d1 = a1 - m32; d1 = d1 * rs32; d1 = d1 * gg;
      float y1 = d1 + bb;
      y1 = y1 >= 0.f ? y1 : 0.2f * y1;
      mx = fmaxf(mx, fmaxf(y0, y1));
    }
    Fo[((size_t)(b * NN + n)) * CC + o] = mx;
  }
}

// ====== final stats: register-blocked GEMM, 64x64 tile, bit-identical h chain ======
// h[n][o] accumulates c = 0..191 strictly ascending (chunk=part 0,1,2; c asc).
template <int CACHE>
__global__ __launch_bounds__(256) void fstats_gemm(const float* __restrict__ F1,
                                                   const float* __restrict__ F2,
                                                   const float* __restrict__ F3,
                                                   const float* __restrict__ Wf,
                                                   double* __restrict__ sums,
                                                   float* __restrict__ hout) {
  __shared__ __align__(16) char smem[34816];
  float* Ft = (float*)smem;                  // [64 c][68 n]
  float* Wt = (float*)(smem + 17408);        // [64 c][68 o]
  int o0 = blockIdx.x * 64;
  int r0 = blockIdx.y * 64;  // flat row = b*NN+n
  int t = threadIdx.x;
  int to = t & 15, tn = t >> 4;
  const float* fs[3] = {F1, F2, F3};

  float acc[4][4] = {};
#pragma unroll 1
  for (int ch = 0; ch < 3; ++ch) {
    __syncthreads();
    // stage weights transposed: Wt[c][o] = Wf[(o0+o)*192 + ch*64 + c]
#pragma unroll
    for (int j = 0; j < 16; ++j) {
      int v = t + 256 * j;  // 0..4095
      int oo = v >> 6, c = v & 63;
      Wt[c * 68 + oo] = Wf[(size_t)(o0 + oo) * 192 + ch * 64 + c];
    }
    // stage features transposed: Ft[c][nn] = fs[ch][(r0+nn)*64 + c]
#pragma unroll
    for (int j = 0; j < 4; ++j) {
      int v = t + 256 * j;
      int row = v >> 4, c4 = (v & 15) * 4;
      float4 val = *(const float4*)(fs[ch] + ((size_t)(r0 + row)) * CC + c4);
      Ft[(c4 + 0) * 68 + row] = val.x;
      Ft[(c4 + 1) * 68 + row] = val.y;
      Ft[(c4 + 2) * 68 + row] = val.z;
      Ft[(c4 + 3) * 68 + row] = val.w;
    }
    __syncthreads();
#pragma unroll 8
    for (int c = 0; c < 64; ++c) {
      float4 av = *(const float4*)&Ft[c * 68 + tn * 4];
      float4 wv = *(const float4*)&Wt[c * 68 + to * 4];
      float a[4] = {av.x, av.y, av.z, av.w};
      float w[4] = {wv.x, wv.y, wv.z, wv.w};
#pragma unroll
      for (int i = 0; i < 4; ++i)
#pragma unroll
        for (int j = 0; j < 4; ++j) acc[i][j] = fmaf(a[i], w[j], acc[i][j]);
    }
  }
  if (CACHE) {
#pragma unroll
    for (int i = 0; i < 4; ++i) {
      float4 hv = {acc[i][0], acc[i][1], acc[i][2], acc[i][3]};
      *(float4*)&hout[((size_t)(r0 + tn * 4 + i)) * OUTC + o0 + to * 4] = hv;
    }
  }
  // per-o partial sums (f64), reduce across tn via LDS overlay
  double sj[4], ssj[4];
#pragma unroll
  for (int j = 0; j < 4; ++j) {
    sj[j] = 0.0; ssj[j] = 0.0;
#pragma unroll
    for (int i = 0; i < 4; ++i) {
      sj[j] += (double)acc[i][j];
      ssj[j] += (double)acc[i][j] * (double)acc[i][j];
    }
  }
  __syncthreads();
  double* reds = (double*)smem;            // [64 o][16 tn] = 8192 B
  double* redss = (double*)(smem + 8192);  // 8192 B
#pragma unroll
  for (int j = 0; j < 4; ++j) {
    reds[(to * 4 + j) * 16 + tn] = sj[j];
    redss[(to * 4 + j) * 16 + tn] = ssj[j];
  }
  __syncthreads();
  if (t < 64) {
    double s = 0.0, ss = 0.0;
#pragma unroll
    for (int u = 0; u < 16; ++u) {
      s += reds[t * 16 + u];
      ss += redss[t * 16 + u];
    }
    atomicAdd(&sums[o0 + t], s);
    atomicAdd(&sums[1024 + o0 + t], ss);
  }
}

// ====== BN finalize (final layer): f64 math -> f32 sc/sh ======
__global__ void finalize_f(const double* __restrict__ sums,
                           const float* __restrict__ g,
                           const float* __restrict__ bb, double cntinv,
                           float* __restrict__ scsh) {
  int c = blockIdx.x * 256 + threadIdx.x;  // 1024
  double mean = sums[c] * cntinv;
  double var = sums[1024 + c] * cntinv - mean * mean;
  double sc = (double)g[c] / sqrt(var + 1e-5);
  scsh[c] = (float)sc;
  scsh[1024 + c] = (float)((double)bb[c] - mean * sc);
}

// ====== final apply from h cache: normalize + partial max over n chunk ======
__global__ __launch_bounds__(256) void fapply_stream(const float* __restrict__ hin,
                                                     const float* __restrict__ scsh,
                                                     float* __restrict__ pmax) {
  int b = blockIdx.y, t = threadIdx.x;
  int o = blockIdx.x * 256 + t;
  int nbase = blockIdx.z * (NN / 8);
  float sc = scsh[o], sh = scsh[1024 + o];
  float mx = -3.0e38f;
  const float* hp = hin + ((size_t)(b * NN + nbase)) * OUTC + o;
#pragma unroll 4
  for (int n = 0; n < NN / 8; ++n) {
    float y = fmaf(sc, hp[(size_t)n * OUTC], sh);
    y = y >= 0.f ? y : 0.2f * y;
    mx = fmaxf(mx, y);
  }
  pmax[((size_t)blockIdx.z * BB + b) * OUTC + o] = mx;
}

__global__ __launch_bounds__(256) void freduce(const float* __restrict__ pmax,
                                               float* __restrict__ out) {
  int v = blockIdx.x * 256 + threadIdx.x;  // b*OUTC+o
  float mx = -3.0e38f;
#pragma unroll
  for (int ch = 0; ch < 8; ++ch) mx = fmaxf(mx, pmax[(size_t)ch * BB * OUTC + v]);
  out[v] = mx;
}

// ====== fallback final apply (no cache) ======
__global__ __launch_bounds__(256) void fapply32(const float* __restrict__ F1,
                                                const float* __restrict__ F2,
                                                const float* __restrict__ F3,
                                                const float* __restrict__ Wf,
                                                const float* __restrict__ scsh,
                                                float* __restrict__ out) {
  __shared__ float Wl[64 * 193];
  __shared__ float redm[4][64];
  int b = blockIdx.y, o0 = blockIdx.x * 64, t = threadIdx.x;
  for (int j = 0; j < 48; ++j) {
    int v = t + 256 * j;
    int oo = v / 192, c = v - oo * 192;
    Wl[oo * 193 + c] = Wf[(size_t)(o0 + oo) * 192 + c];
  }
  __syncthreads();
  int o = t & 63, g = t >> 6;
  float sc = scsh[o0 + o], sh = scsh[1024 + o0 + o];
  const float* fs[3] = {F1, F2, F3};
  float mx = -3.0e38f;
  for (int n0 = 0; n0 < NN; n0 += 16) {
    int n = n0 + g * 4;
    float h[4] = {0.f, 0.f, 0.f, 0.f};
#pragma unroll
    for (int part = 0; part < 3; ++part) {
      const float* src = fs[part] + ((size_t)(b * NN + n)) * CC;
      const float* wp = &Wl[o * 193 + part * 64];
#pragma unroll 4
      for (int c4 = 0; c4 < 16; ++c4) {
        float4 w4 = {wp[c4 * 4], wp[c4 * 4 + 1], wp[c4 * 4 + 2], wp[c4 * 4 + 3]};
#pragma unroll
        for (int i = 0; i < 4; ++i) {
          float4 v = *(const float4*)(src + (size_t)i * CC + c4 * 4);
          h[i] = fmaf(w4.x, v.x, h[i]);
          h[i] = fmaf(w4.y, v.y, h[i]);
          h[i] = fmaf(w4.z, v.z, h[i]);
          h[i] = fmaf(w4.w, v.w, h[i]);
        }
      }
    }
#pragma unroll
    for (int i = 0; i < 4; ++i) {
      float y = fmaf(sc, h[i], sh);
      y = y >= 0.f ? y : 0.2f * y;
      mx = fmaxf(mx, y);
    }
  }
  redm[g][o] = mx;
  __syncthreads();
  if (t < 64) {
    float m = fmaxf(fmaxf(redm[0][o], redm[1][o]), fmaxf(redm[2][o], redm[3][o]));
    out[(size_t)b * OUTC + o0 + o] = m;
  }
}

extern "C" void kernel_launch(void* const* d_in, const int* in_sizes, int n_in,
                              void* d_out, int out_size, void* d_ws, size_t ws_size,
                              hipStream_t stream) {
  (void)in_sizes; (void)n_in; (void)out_size;
  const float* x  = (const float*)d_in[0];
  const float* W1 = (const float*)d_in[1];
  const float* g1 = (const float*)d_in[2];
  const float* b1 = (const float*)d_in[3];
  const float* W2 = (const float*)d_in[4];
  const float* g2 = (const float*)d_in[5];
  const float* b2 = (const float*)d_in[6];
  const float* W3 = (const float*)d_in[7];
  const float* g3 = (const float*)d_in[8];
  const float* b3 = (const float*)d_in[9];
  const float* Wf = (const float*)d_in[10];
  const float* gf = (const float*)d_in[11];
  const float* bf = (const float*)d_in[12];
  float* out = (float*)d_out;

  char* wsb = (char*)d_ws;
  float* F1f    = (float*)(wsb + 0);           // 8 MB
  float* F2f    = (float*)(wsb + 8388608);     // 8 MB
  float* F3f    = (float*)(wsb + 16777216);    // 8 MB
  float* xxf    = (float*)(wsb + 25165824);    // 128 KB
  int* idx      = (int*)(wsb + 25296896);      // 2.62 MB
  double* sumsd = (double*)(wsb + 27918336);   // 128 doubles
  double* fsums = (double*)(wsb + 27920384);   // 2048 doubles
  float* fscsh  = (float*)(wsb + 27936768);    // 2048 floats
  float* mrs    = (float*)(wsb + 27944960);    // 128 floats
  float* pmax   = (float*)(wsb + 27945984);    // 512 KB
  float* hbuf   = (float*)(wsb + 29360128);    // 167.8 MB (optional)
  const bool cache = ws_size >= (size_t)29360128 + (size_t)BB * NN * KNN * 64 * 4;

  const float* Fin[3] = {x, F1f, F2f};
  float* Fout[3] = {F1f, F2f, F3f};
  const float* Ws[3] = {W1, W2, W3};
  const float* gs[3] = {g1, g2, g3};
  const float* bs[3] = {b1, b2, b3};

  for (int L = 0; L < 3; ++L) {
    xx32_kernel<<<dim3(BB * NN / 256), 256, 0, stream>>>(Fin[L], xxf);
    knn_fast<<<dim3(NN / 64, BB), 256, 0, stream>>>(Fin[L], xxf, idx);
    hipMemsetAsync(sumsd, 0, 128 * sizeof(double), stream);
    if (cache)
      stats_k<1><<<dim3(NN / 64, BB), 256, 0, stream>>>(Fin[L], Ws[L], idx, sumsd, hbuf);
    else
      stats_k<0><<<dim3(NN / 64, BB), 256, 0, stream>>>(Fin[L], Ws[L], idx, sumsd, nullptr);
    finalize_np<<<1, 64, 0, stream>>>(sumsd, 1.0 / (double)(BB * NN * KNN), mrs);
    if (cache)
      apply_cached<<<dim3(BB * NN / 4), 256, 0, stream>>>(hbuf, mrs, gs[L], bs[L], Fout[L]);
    else
      apply_rec<<<dim3(NN / 64, BB), 256, 0, stream>>>(Fin[L], Ws[L], idx, mrs,
                                                       gs[L], bs[L], Fout[L]);
  }
  hipMemsetAsync(fsums, 0, 2048 * sizeof(double), stream);
  if (cache) {
    fstats_gemm<1><<<dim3(OUTC / 64, BB * NN / 64), 256, 0, stream>>>(F1f, F2f, F3f,
                                                                      Wf, fsums, hbuf);
    finalize_f<<<4, 256, 0, stream>>>(fsums, gf, bf, 1.0 / (double)(BB * NN), fscsh);
    fapply_stream<<<dim3(OUTC / 256, BB, 8), 256, 0, stream>>>(hbuf, fscsh, pmax);
    freduce<<<dim3(BB * OUTC / 256), 256, 0, stream>>>(pmax, out);
  } else {
    fstats_gemm<0><<<dim3(OUTC / 64, BB * NN / 64), 256, 0, stream>>>(F1f, F2f, F3f,
                                                                      Wf, fsums, nullptr);
    finalize_f<<<4, 256, 0, stream>>>(fsums, gf, bf, 1.0 / (double)(BB * NN), fscsh);
    fapply32<<<dim3(OUTC / 64, BB), 256, 0, stream>>>(F1f, F2f, F3f, Wf, fscsh, out);
  }
}